// Round 1
// baseline (1899.210 us; speedup 1.0000x reference)
//
#include <hip/hip_runtime.h>
#include <hip/hip_bf16.h>

#define NN   100000
#define EE   1600000
#define ETOT (EE + NN)
#define GG   256
#define BNEPS 1e-5f

// ---------------- CSR build ----------------

__global__ void hist_kernel(const int* __restrict__ ei, int* __restrict__ deg) {
    int i = blockIdx.x * blockDim.x + threadIdx.x;
    if (i >= ETOT) return;
    int dst = (i < EE) ? ei[EE + i] : (i - EE);
    atomicAdd(&deg[dst], 1);
}

__global__ void scan1_kernel(const int* __restrict__ deg, int* __restrict__ row_ptr,
                             int* __restrict__ bsum) {
    __shared__ int sdata[256];
    int i = blockIdx.x * 256 + threadIdx.x;
    int v = (i < NN) ? deg[i] : 0;
    sdata[threadIdx.x] = v;
    __syncthreads();
    int x = v;
    for (int off = 1; off < 256; off <<= 1) {
        int y = (threadIdx.x >= off) ? sdata[threadIdx.x - off] : 0;
        __syncthreads();
        x += y;
        sdata[threadIdx.x] = x;
        __syncthreads();
    }
    if (i < NN) row_ptr[i] = x - v;  // exclusive scan within block
    if (threadIdx.x == 255) bsum[blockIdx.x] = x;
}

__global__ void scan2_kernel(int* __restrict__ bsum, int nb) {
    if (threadIdx.x == 0 && blockIdx.x == 0) {
        int acc = 0;
        for (int i = 0; i < nb; ++i) { int t = bsum[i]; bsum[i] = acc; acc += t; }
    }
}

__global__ void scan3_kernel(int* __restrict__ row_ptr, const int* __restrict__ bsum,
                             int* __restrict__ cursor) {
    int i = blockIdx.x * 256 + threadIdx.x;
    if (i < NN) {
        int v = row_ptr[i] + bsum[blockIdx.x];
        row_ptr[i] = v;
        cursor[i] = v;
    }
    if (i == 0 && blockIdx.x == 0) row_ptr[NN] = ETOT;
}

__global__ void fill_kernel(const int* __restrict__ ei, int* __restrict__ cursor,
                            int* __restrict__ csr_src) {
    int i = blockIdx.x * blockDim.x + threadIdx.x;
    if (i >= ETOT) return;
    int src, dst;
    if (i < EE) { src = ei[i]; dst = ei[EE + i]; }
    else        { src = i - EE; dst = i - EE; }
    int pos = atomicAdd(&cursor[dst], 1);
    csr_src[pos] = src;
}

// ---------------- per-layer feature transform ----------------
// h = x@W ; e_src/e_dst via wave reduction ; rout = x@pw + pb (residual, pre-written
// into the layer-output buffer so the aggregate kernel can +=).

template<int F_IN, int F_OUT>
__global__ __launch_bounds__(256) void feat_kernel(
    const float* __restrict__ xin, const float* __restrict__ W,
    const float* __restrict__ pw, const float* __restrict__ pb,
    const float* __restrict__ a_src, const float* __restrict__ a_dst,
    float* __restrict__ h, float* __restrict__ esrc, float* __restrict__ edst,
    float* __restrict__ rout, int nN)
{
    constexpr int NPB = 256 / F_OUT;
    int t = threadIdx.x;
    int n = blockIdx.x * NPB + t / F_OUT;
    int f = t % F_OUT;
    if (n >= nN) return;
    float acc = 0.f, racc = 0.f;
#pragma unroll 8
    for (int k = 0; k < F_IN; ++k) {
        float xv = xin[n * F_IN + k];
        acc  += xv * W[k * F_OUT + f];
        racc += xv * pw[k * F_OUT + f];
    }
    h[n * F_OUT + f]    = acc;
    rout[n * F_OUT + f] = racc + pb[f];
    float es = acc * a_src[f];
    float ed = acc * a_dst[f];
    constexpr int C  = F_OUT / 2;
    constexpr int RW = (C < 64) ? C : 64;  // reduction segment width
#pragma unroll
    for (int off = RW >> 1; off > 0; off >>= 1) {
        es += __shfl_xor(es, off, RW);
        ed += __shfl_xor(ed, off, RW);
    }
    if ((t % RW) == 0) {
        int head = f / C;
        esrc[n * 2 + head] = es;
        edst[n * 2 + head] = ed;
    }
}

// ---------------- fused softmax-aggregate + bias + BN + ReLU + residual ----------------
// One wave per dst node. exp(alpha) without max-subtraction (mathematically identical,
// alpha bounded to a few units for this parameterization).

template<int F_OUT>
__global__ __launch_bounds__(256) void aggregate_kernel(
    const float* __restrict__ h, const float2* __restrict__ esrc,
    const float2* __restrict__ edst,
    const int* __restrict__ row_ptr, const int* __restrict__ csr_src,
    const float* __restrict__ bias, const float* __restrict__ bng,
    const float* __restrict__ bnb, const float* __restrict__ bnm,
    const float* __restrict__ bnv, float* __restrict__ out, int nN)
{
    int w = threadIdx.x >> 6;
    int lane = threadIdx.x & 63;
    int n = blockIdx.x * 4 + w;
    if (n >= nN) return;
    float2 ed = edst[n];
    int jb = row_ptr[n], je = row_ptr[n + 1];
    float s0 = 0.f, s1 = 0.f, acc0 = 0.f, acc1 = 0.f;
    for (int j = jb; j < je; ++j) {
        int src = csr_src[j];
        float2 es = esrc[src];
        float a0 = es.x + ed.x; a0 = (a0 > 0.f) ? a0 : 0.2f * a0;
        float a1 = es.y + ed.y; a1 = (a1 > 0.f) ? a1 : 0.2f * a1;
        float w0 = __expf(a0), w1 = __expf(a1);
        if (F_OUT == 128) {
            acc0 += w0 * h[src * 128 + lane];
            acc1 += w1 * h[src * 128 + 64 + lane];
        } else {
            float wv = (lane < 32) ? w0 : w1;
            acc0 += wv * h[src * 64 + lane];
        }
        s0 += w0; s1 += w1;
    }
    if (F_OUT == 128) {
        int f0 = lane, f1 = lane + 64;
        float g0 = acc0 / (s0 + 1e-16f);
        float g1 = acc1 / (s1 + 1e-16f);
        float v0 = bng[f0] * (g0 + bias[f0] - bnm[f0]) * rsqrtf(bnv[f0] + BNEPS) + bnb[f0];
        float v1 = bng[f1] * (g1 + bias[f1] - bnm[f1]) * rsqrtf(bnv[f1] + BNEPS) + bnb[f1];
        out[n * 128 + f0] = fmaxf(v0, 0.f) + out[n * 128 + f0];
        out[n * 128 + f1] = fmaxf(v1, 0.f) + out[n * 128 + f1];
    } else {
        int f = lane;
        float s = (lane < 32) ? s0 : s1;
        float g = acc0 / (s + 1e-16f);
        float v = bng[f] * (g + bias[f] - bnm[f]) * rsqrtf(bnv[f] + BNEPS) + bnb[f];
        out[n * 64 + f] = fmaxf(v, 0.f) + out[n * 64 + f];
    }
}

// ---------------- pooling (segment mean over sorted batch) ----------------

__global__ __launch_bounds__(128) void pool_kernel(const float* __restrict__ hfin,
                                                   const int* __restrict__ batch,
                                                   float* __restrict__ pooled) {
    int g = blockIdx.x;
    int f = threadIdx.x;
    int lo = 0, hi = NN;
    while (lo < hi) { int mid = (lo + hi) >> 1; if (batch[mid] < g) lo = mid + 1; else hi = mid; }
    int start = lo;
    hi = NN;
    while (lo < hi) { int mid = (lo + hi) >> 1; if (batch[mid] < g + 1) lo = mid + 1; else hi = mid; }
    int end = lo;
    float acc = 0.f;
    for (int i = start; i < end; ++i) acc += hfin[i * 128 + f];
    float cnt = (float)(end - start);
    pooled[g * 128 + f] = acc / fmaxf(cnt, 1.0f);
}

// ---------------- MLP head: bn(pooled@fw+fb) relu -> l1 relu -> l2 ----------------

__global__ __launch_bounds__(128) void head_kernel(
    const float* __restrict__ pooled, const float* __restrict__ fw, const float* __restrict__ fb,
    const float* __restrict__ g4, const float* __restrict__ be4,
    const float* __restrict__ m4, const float* __restrict__ v4,
    const float* __restrict__ l1w, const float* __restrict__ l1b,
    const float* __restrict__ l2w, const float* __restrict__ l2b,
    float* __restrict__ out)
{
    __shared__ float p[128];
    __shared__ float z1[32];
    __shared__ float z2[32];
    int g = blockIdx.x, t = threadIdx.x;
    p[t] = pooled[g * 128 + t];
    __syncthreads();
    if (t < 32) {
        float acc = fb[t];
        for (int k = 0; k < 128; ++k) acc += p[k] * fw[k * 32 + t];
        float val = g4[t] * (acc - m4[t]) * rsqrtf(v4[t] + BNEPS) + be4[t];
        z1[t] = fmaxf(val, 0.f);
    }
    __syncthreads();
    if (t < 32) {
        float acc = l1b[t];
        for (int k = 0; k < 32; ++k) acc += z1[k] * l1w[k * 32 + t];
        z2[t] = fmaxf(acc, 0.f);
    }
    __syncthreads();
    if (t < 10) {
        float acc = l2b[t];
        for (int k = 0; k < 32; ++k) acc += z2[k] * l2w[k * 10 + t];
        out[g * 10 + t] = acc;
    }
}

// ---------------- launch ----------------

extern "C" void kernel_launch(void* const* d_in, const int* in_sizes, int n_in,
                              void* d_out, int out_size, void* d_ws, size_t ws_size,
                              hipStream_t stream) {
    const float* x     = (const float*)d_in[0];
    const int*   ei    = (const int*)d_in[1];
    const int*   batch = (const int*)d_in[2];
    const float* w1  = (const float*)d_in[3];
    const float* as1 = (const float*)d_in[4];
    const float* ad1 = (const float*)d_in[5];
    const float* b1  = (const float*)d_in[6];
    const float* g1  = (const float*)d_in[7];
    const float* be1 = (const float*)d_in[8];
    const float* m1  = (const float*)d_in[9];
    const float* v1  = (const float*)d_in[10];
    const float* p1w = (const float*)d_in[11];
    const float* p1b = (const float*)d_in[12];
    const float* w2  = (const float*)d_in[13];
    const float* as2 = (const float*)d_in[14];
    const float* ad2 = (const float*)d_in[15];
    const float* b2  = (const float*)d_in[16];
    const float* g2  = (const float*)d_in[17];
    const float* be2 = (const float*)d_in[18];
    const float* m2  = (const float*)d_in[19];
    const float* v2  = (const float*)d_in[20];
    const float* p2w = (const float*)d_in[21];
    const float* p2b = (const float*)d_in[22];
    const float* w3  = (const float*)d_in[23];
    const float* as3 = (const float*)d_in[24];
    const float* ad3 = (const float*)d_in[25];
    const float* b3  = (const float*)d_in[26];
    const float* g3  = (const float*)d_in[27];
    const float* be3 = (const float*)d_in[28];
    const float* m3  = (const float*)d_in[29];
    const float* v3  = (const float*)d_in[30];
    const float* p3w = (const float*)d_in[31];
    const float* p3b = (const float*)d_in[32];
    const float* fw  = (const float*)d_in[33];
    const float* fb  = (const float*)d_in[34];
    const float* g4  = (const float*)d_in[35];
    const float* be4 = (const float*)d_in[36];
    const float* m4  = (const float*)d_in[37];
    const float* v4  = (const float*)d_in[38];
    const float* l1w = (const float*)d_in[39];
    const float* l1b = (const float*)d_in[40];
    const float* l2w = (const float*)d_in[41];
    const float* l2b = (const float*)d_in[42];

    char* ws = (char*)d_ws;
    size_t off = 0;
    auto alloc = [&](size_t bytes) -> char* {
        char* p = ws + off;
        off += (bytes + 255) & ~(size_t)255;
        return p;
    };
    int*   deg     = (int*)alloc(NN * sizeof(int));
    int*   row_ptr = (int*)alloc((NN + 1) * sizeof(int));
    int*   cursor  = (int*)alloc(NN * sizeof(int));
    int*   bsum    = (int*)alloc(4096 * sizeof(int));
    int*   csr_src = (int*)alloc((size_t)ETOT * sizeof(int));
    float* bufA    = (float*)alloc((size_t)NN * 128 * sizeof(float));
    float* bufB    = (float*)alloc((size_t)NN * 128 * sizeof(float));
    float* bufC    = (float*)alloc((size_t)NN * 128 * sizeof(float));
    float* esrc    = (float*)alloc((size_t)NN * 2 * sizeof(float));
    float* edst    = (float*)alloc((size_t)NN * 2 * sizeof(float));
    float* pooled  = (float*)alloc((size_t)GG * 128 * sizeof(float));

    // ---- CSR build (by dst) ----
    hipMemsetAsync(deg, 0, NN * sizeof(int), stream);
    hist_kernel<<<(ETOT + 255) / 256, 256, 0, stream>>>(ei, deg);
    constexpr int NB = (NN + 255) / 256;
    scan1_kernel<<<NB, 256, 0, stream>>>(deg, row_ptr, bsum);
    scan2_kernel<<<1, 64, 0, stream>>>(bsum, NB);
    scan3_kernel<<<NB, 256, 0, stream>>>(row_ptr, bsum, cursor);
    fill_kernel<<<(ETOT + 255) / 256, 256, 0, stream>>>(ei, cursor, csr_src);

    // ---- layer 1: x[N,5] -> bufB[N,64] ----
    feat_kernel<5, 64><<<(NN + 3) / 4, 256, 0, stream>>>(
        x, w1, p1w, p1b, as1, ad1, bufA, esrc, edst, bufB, NN);
    aggregate_kernel<64><<<(NN + 3) / 4, 256, 0, stream>>>(
        bufA, (const float2*)esrc, (const float2*)edst, row_ptr, csr_src,
        b1, g1, be1, m1, v1, bufB, NN);

    // ---- layer 2: bufB[N,64] -> bufC[N,128] ----
    feat_kernel<64, 128><<<(NN + 1) / 2, 256, 0, stream>>>(
        bufB, w2, p2w, p2b, as2, ad2, bufA, esrc, edst, bufC, NN);
    aggregate_kernel<128><<<(NN + 3) / 4, 256, 0, stream>>>(
        bufA, (const float2*)esrc, (const float2*)edst, row_ptr, csr_src,
        b2, g2, be2, m2, v2, bufC, NN);

    // ---- layer 3: bufC[N,128] -> bufB[N,128] ----
    feat_kernel<128, 128><<<(NN + 1) / 2, 256, 0, stream>>>(
        bufC, w3, p3w, p3b, as3, ad3, bufA, esrc, edst, bufB, NN);
    aggregate_kernel<128><<<(NN + 3) / 4, 256, 0, stream>>>(
        bufA, (const float2*)esrc, (const float2*)edst, row_ptr, csr_src,
        b3, g3, be3, m3, v3, bufB, NN);

    // ---- pool + head ----
    pool_kernel<<<GG, 128, 0, stream>>>(bufB, batch, pooled);
    head_kernel<<<GG, 128, 0, stream>>>(pooled, fw, fb, g4, be4, m4, v4,
                                        l1w, l1b, l2w, l2b, (float*)d_out);
}

// Round 2
// 1263.376 us; speedup vs baseline: 1.5033x; 1.5033x over previous
//
#include <hip/hip_runtime.h>
#include <hip/hip_bf16.h>

#define NN   100000
#define EE   1600000
#define ETOT (EE + NN)
#define GG   256
#define BNEPS 1e-5f

// ---------------- CSR build ----------------

__global__ void hist_kernel(const int* __restrict__ ei, int* __restrict__ deg) {
    int i = blockIdx.x * blockDim.x + threadIdx.x;
    if (i >= ETOT) return;
    int dst = (i < EE) ? ei[EE + i] : (i - EE);
    atomicAdd(&deg[dst], 1);
}

__global__ void scan1_kernel(const int* __restrict__ deg, int* __restrict__ row_ptr,
                             int* __restrict__ bsum) {
    __shared__ int sdata[256];
    int i = blockIdx.x * 256 + threadIdx.x;
    int v = (i < NN) ? deg[i] : 0;
    sdata[threadIdx.x] = v;
    __syncthreads();
    int x = v;
    for (int off = 1; off < 256; off <<= 1) {
        int y = (threadIdx.x >= off) ? sdata[threadIdx.x - off] : 0;
        __syncthreads();
        x += y;
        sdata[threadIdx.x] = x;
        __syncthreads();
    }
    if (i < NN) row_ptr[i] = x - v;  // exclusive scan within block
    if (threadIdx.x == 255) bsum[blockIdx.x] = x;
}

__global__ void scan2_kernel(int* __restrict__ bsum, int nb) {
    if (threadIdx.x == 0 && blockIdx.x == 0) {
        int acc = 0;
        for (int i = 0; i < nb; ++i) { int t = bsum[i]; bsum[i] = acc; acc += t; }
    }
}

__global__ void scan3_kernel(int* __restrict__ row_ptr, const int* __restrict__ bsum,
                             int* __restrict__ cursor) {
    int i = blockIdx.x * 256 + threadIdx.x;
    if (i < NN) {
        int v = row_ptr[i] + bsum[blockIdx.x];
        row_ptr[i] = v;
        cursor[i] = v;
    }
    if (i == 0 && blockIdx.x == 0) row_ptr[NN] = ETOT;
}

__global__ void fill_kernel(const int* __restrict__ ei, int* __restrict__ cursor,
                            int* __restrict__ csr_src) {
    int i = blockIdx.x * blockDim.x + threadIdx.x;
    if (i >= ETOT) return;
    int src, dst;
    if (i < EE) { src = ei[i]; dst = ei[EE + i]; }
    else        { src = i - EE; dst = i - EE; }
    int pos = atomicAdd(&cursor[dst], 1);
    csr_src[pos] = src;
}

// ---------------- layer-1 feature transform (K=5, cheap) ----------------

template<int F_IN, int F_OUT>
__global__ __launch_bounds__(256) void feat_kernel(
    const float* __restrict__ xin, const float* __restrict__ W,
    const float* __restrict__ pw, const float* __restrict__ pb,
    const float* __restrict__ a_src, const float* __restrict__ a_dst,
    float* __restrict__ h, float* __restrict__ esrc, float* __restrict__ edst,
    float* __restrict__ rout, int nN)
{
    constexpr int NPB = 256 / F_OUT;
    int t = threadIdx.x;
    int n = blockIdx.x * NPB + t / F_OUT;
    int f = t % F_OUT;
    if (n >= nN) return;
    float acc = 0.f, racc = 0.f;
#pragma unroll
    for (int k = 0; k < F_IN; ++k) {
        float xv = xin[n * F_IN + k];
        acc  += xv * W[k * F_OUT + f];
        racc += xv * pw[k * F_OUT + f];
    }
    h[n * F_OUT + f]    = acc;
    rout[n * F_OUT + f] = racc + pb[f];
    float es = acc * a_src[f];
    float ed = acc * a_dst[f];
    constexpr int C  = F_OUT / 2;
    constexpr int RW = (C < 64) ? C : 64;  // reduction segment width
#pragma unroll
    for (int off = RW >> 1; off > 0; off >>= 1) {
        es += __shfl_xor(es, off, RW);
        ed += __shfl_xor(ed, off, RW);
    }
    if ((t % RW) == 0) {
        int head = f / C;
        esrc[n * 2 + head] = es;
        edst[n * 2 + head] = ed;
    }
}

// ---------------- register-tiled feature transform (layers 2,3; F_OUT=128) ----
// Block = 256 threads → 16 nodes × 256 output cols (h[0:128] ‖ rout[0:128]).
// Thread = (nt = tid/64 node-group of 4, ft = tid&63 → 4 cols).
// x-tile staged in LDS (contiguous copy); weights streamed 1 KB per k per block
// (vs 512 B per k per WAVE before — that was the L2-BW bottleneck).

template<int F_IN>
__global__ __launch_bounds__(256) void tiled_feat_kernel(
    const float* __restrict__ xin, const float* __restrict__ W,
    const float* __restrict__ pw, const float* __restrict__ pb,
    const float* __restrict__ a_src, const float* __restrict__ a_dst,
    float* __restrict__ h, float* __restrict__ esrc, float* __restrict__ edst,
    float* __restrict__ rout)
{
    constexpr int F_OUT = 128;
    constexpr int TILE_M = 16;
    constexpr int K4 = F_IN / 4;
    __shared__ float4 xs4[TILE_M * K4];

    const int tid = threadIdx.x;
    const int ft = tid & 63;
    const int nt = tid >> 6;            // 0..3
    const int base = blockIdx.x * TILE_M;

    // cooperative contiguous copy of the 16-node x tile into LDS
    const float4* xg = (const float4*)(xin + (size_t)base * F_IN);
    constexpr int NV = TILE_M * K4;
#pragma unroll
    for (int i = tid; i < NV; i += 256) xs4[i] = xg[i];
    __syncthreads();

    const int col4 = ft * 4;
    const bool isW = (col4 < F_OUT);
    const float* wbase = isW ? W : pw;
    const int f = isW ? col4 : (col4 - F_OUT);

    float4 acc[4];
#pragma unroll
    for (int i = 0; i < 4; ++i) acc[i] = make_float4(0.f, 0.f, 0.f, 0.f);

    for (int k0 = 0; k0 < F_IN; k0 += 4) {
        float4 w0 = *(const float4*)(wbase + (size_t)(k0 + 0) * F_OUT + f);
        float4 w1 = *(const float4*)(wbase + (size_t)(k0 + 1) * F_OUT + f);
        float4 w2 = *(const float4*)(wbase + (size_t)(k0 + 2) * F_OUT + f);
        float4 w3 = *(const float4*)(wbase + (size_t)(k0 + 3) * F_OUT + f);
        float4 xv[4];
#pragma unroll
        for (int i = 0; i < 4; ++i) xv[i] = xs4[(nt * 4 + i) * K4 + (k0 >> 2)];
#pragma unroll
        for (int i = 0; i < 4; ++i) {
            acc[i].x = fmaf(xv[i].x, w0.x, acc[i].x);
            acc[i].y = fmaf(xv[i].x, w0.y, acc[i].y);
            acc[i].z = fmaf(xv[i].x, w0.z, acc[i].z);
            acc[i].w = fmaf(xv[i].x, w0.w, acc[i].w);
            acc[i].x = fmaf(xv[i].y, w1.x, acc[i].x);
            acc[i].y = fmaf(xv[i].y, w1.y, acc[i].y);
            acc[i].z = fmaf(xv[i].y, w1.z, acc[i].z);
            acc[i].w = fmaf(xv[i].y, w1.w, acc[i].w);
            acc[i].x = fmaf(xv[i].z, w2.x, acc[i].x);
            acc[i].y = fmaf(xv[i].z, w2.y, acc[i].y);
            acc[i].z = fmaf(xv[i].z, w2.z, acc[i].z);
            acc[i].w = fmaf(xv[i].z, w2.w, acc[i].w);
            acc[i].x = fmaf(xv[i].w, w3.x, acc[i].x);
            acc[i].y = fmaf(xv[i].w, w3.y, acc[i].y);
            acc[i].z = fmaf(xv[i].w, w3.z, acc[i].z);
            acc[i].w = fmaf(xv[i].w, w3.w, acc[i].w);
        }
    }

    if (isW) {
#pragma unroll
        for (int i = 0; i < 4; ++i) {
            int node = base + nt * 4 + i;
            *(float4*)(h + (size_t)node * F_OUT + f) = acc[i];
        }
        // attention logits: dot over this thread's 4 channels, reduce over the
        // 16 lanes that own one head (head0 = lanes 0-15, head1 = lanes 16-31)
        float4 av = *(const float4*)(a_src + f);
        float4 dv = *(const float4*)(a_dst + f);
#pragma unroll
        for (int i = 0; i < 4; ++i) {
            float es = acc[i].x * av.x + acc[i].y * av.y + acc[i].z * av.z + acc[i].w * av.w;
            float ed = acc[i].x * dv.x + acc[i].y * dv.y + acc[i].z * dv.z + acc[i].w * dv.w;
#pragma unroll
            for (int off = 8; off > 0; off >>= 1) {
                es += __shfl_xor(es, off, 16);
                ed += __shfl_xor(ed, off, 16);
            }
            if ((ft & 15) == 0) {
                int node = base + nt * 4 + i;
                int head = ft >> 4;   // 0 or 1
                esrc[node * 2 + head] = es;
                edst[node * 2 + head] = ed;
            }
        }
    } else {
        float4 bv = *(const float4*)(pb + f);
#pragma unroll
        for (int i = 0; i < 4; ++i) {
            int node = base + nt * 4 + i;
            float4 r = acc[i];
            r.x += bv.x; r.y += bv.y; r.z += bv.z; r.w += bv.w;
            *(float4*)(rout + (size_t)node * F_OUT + f) = r;
        }
    }
}

// ---------------- fused softmax-aggregate + bias + BN + ReLU + residual ----------------
// One wave per dst node. exp(alpha) without max-subtraction (mathematically identical,
// alpha bounded to a few units for this parameterization).

template<int F_OUT>
__global__ __launch_bounds__(256) void aggregate_kernel(
    const float* __restrict__ h, const float2* __restrict__ esrc,
    const float2* __restrict__ edst,
    const int* __restrict__ row_ptr, const int* __restrict__ csr_src,
    const float* __restrict__ bias, const float* __restrict__ bng,
    const float* __restrict__ bnb, const float* __restrict__ bnm,
    const float* __restrict__ bnv, float* __restrict__ out, int nN)
{
    int w = threadIdx.x >> 6;
    int lane = threadIdx.x & 63;
    int n = blockIdx.x * 4 + w;
    if (n >= nN) return;
    float2 ed = edst[n];
    int jb = row_ptr[n], je = row_ptr[n + 1];
    float s0 = 0.f, s1 = 0.f, acc0 = 0.f, acc1 = 0.f;
    for (int j = jb; j < je; ++j) {
        int src = csr_src[j];
        float2 es = esrc[src];
        float a0 = es.x + ed.x; a0 = (a0 > 0.f) ? a0 : 0.2f * a0;
        float a1 = es.y + ed.y; a1 = (a1 > 0.f) ? a1 : 0.2f * a1;
        float w0 = __expf(a0), w1 = __expf(a1);
        if (F_OUT == 128) {
            acc0 += w0 * h[src * 128 + lane];
            acc1 += w1 * h[src * 128 + 64 + lane];
        } else {
            float wv = (lane < 32) ? w0 : w1;
            acc0 += wv * h[src * 64 + lane];
        }
        s0 += w0; s1 += w1;
    }
    if (F_OUT == 128) {
        int f0 = lane, f1 = lane + 64;
        float g0 = acc0 / (s0 + 1e-16f);
        float g1 = acc1 / (s1 + 1e-16f);
        float v0 = bng[f0] * (g0 + bias[f0] - bnm[f0]) * rsqrtf(bnv[f0] + BNEPS) + bnb[f0];
        float v1 = bng[f1] * (g1 + bias[f1] - bnm[f1]) * rsqrtf(bnv[f1] + BNEPS) + bnb[f1];
        out[n * 128 + f0] = fmaxf(v0, 0.f) + out[n * 128 + f0];
        out[n * 128 + f1] = fmaxf(v1, 0.f) + out[n * 128 + f1];
    } else {
        int f = lane;
        float s = (lane < 32) ? s0 : s1;
        float g = acc0 / (s + 1e-16f);
        float v = bng[f] * (g + bias[f] - bnm[f]) * rsqrtf(bnv[f] + BNEPS) + bnb[f];
        out[n * 64 + f] = fmaxf(v, 0.f) + out[n * 64 + f];
    }
}

// ---------------- pooling (segment mean over sorted batch) ----------------

__global__ __launch_bounds__(128) void pool_kernel(const float* __restrict__ hfin,
                                                   const int* __restrict__ batch,
                                                   float* __restrict__ pooled) {
    int g = blockIdx.x;
    int f = threadIdx.x;
    int lo = 0, hi = NN;
    while (lo < hi) { int mid = (lo + hi) >> 1; if (batch[mid] < g) lo = mid + 1; else hi = mid; }
    int start = lo;
    hi = NN;
    while (lo < hi) { int mid = (lo + hi) >> 1; if (batch[mid] < g + 1) lo = mid + 1; else hi = mid; }
    int end = lo;
    float acc = 0.f;
    for (int i = start; i < end; ++i) acc += hfin[i * 128 + f];
    float cnt = (float)(end - start);
    pooled[g * 128 + f] = acc / fmaxf(cnt, 1.0f);
}

// ---------------- MLP head: bn(pooled@fw+fb) relu -> l1 relu -> l2 ----------------

__global__ __launch_bounds__(128) void head_kernel(
    const float* __restrict__ pooled, const float* __restrict__ fw, const float* __restrict__ fb,
    const float* __restrict__ g4, const float* __restrict__ be4,
    const float* __restrict__ m4, const float* __restrict__ v4,
    const float* __restrict__ l1w, const float* __restrict__ l1b,
    const float* __restrict__ l2w, const float* __restrict__ l2b,
    float* __restrict__ out)
{
    __shared__ float p[128];
    __shared__ float z1[32];
    __shared__ float z2[32];
    int g = blockIdx.x, t = threadIdx.x;
    p[t] = pooled[g * 128 + t];
    __syncthreads();
    if (t < 32) {
        float acc = fb[t];
        for (int k = 0; k < 128; ++k) acc += p[k] * fw[k * 32 + t];
        float val = g4[t] * (acc - m4[t]) * rsqrtf(v4[t] + BNEPS) + be4[t];
        z1[t] = fmaxf(val, 0.f);
    }
    __syncthreads();
    if (t < 32) {
        float acc = l1b[t];
        for (int k = 0; k < 32; ++k) acc += z1[k] * l1w[k * 32 + t];
        z2[t] = fmaxf(acc, 0.f);
    }
    __syncthreads();
    if (t < 10) {
        float acc = l2b[t];
        for (int k = 0; k < 32; ++k) acc += z2[k] * l2w[k * 10 + t];
        out[g * 10 + t] = acc;
    }
}

// ---------------- launch ----------------

extern "C" void kernel_launch(void* const* d_in, const int* in_sizes, int n_in,
                              void* d_out, int out_size, void* d_ws, size_t ws_size,
                              hipStream_t stream) {
    const float* x     = (const float*)d_in[0];
    const int*   ei    = (const int*)d_in[1];
    const int*   batch = (const int*)d_in[2];
    const float* w1  = (const float*)d_in[3];
    const float* as1 = (const float*)d_in[4];
    const float* ad1 = (const float*)d_in[5];
    const float* b1  = (const float*)d_in[6];
    const float* g1  = (const float*)d_in[7];
    const float* be1 = (const float*)d_in[8];
    const float* m1  = (const float*)d_in[9];
    const float* v1  = (const float*)d_in[10];
    const float* p1w = (const float*)d_in[11];
    const float* p1b = (const float*)d_in[12];
    const float* w2  = (const float*)d_in[13];
    const float* as2 = (const float*)d_in[14];
    const float* ad2 = (const float*)d_in[15];
    const float* b2  = (const float*)d_in[16];
    const float* g2  = (const float*)d_in[17];
    const float* be2 = (const float*)d_in[18];
    const float* m2  = (const float*)d_in[19];
    const float* v2  = (const float*)d_in[20];
    const float* p2w = (const float*)d_in[21];
    const float* p2b = (const float*)d_in[22];
    const float* w3  = (const float*)d_in[23];
    const float* as3 = (const float*)d_in[24];
    const float* ad3 = (const float*)d_in[25];
    const float* b3  = (const float*)d_in[26];
    const float* g3  = (const float*)d_in[27];
    const float* be3 = (const float*)d_in[28];
    const float* m3  = (const float*)d_in[29];
    const float* v3  = (const float*)d_in[30];
    const float* p3w = (const float*)d_in[31];
    const float* p3b = (const float*)d_in[32];
    const float* fw  = (const float*)d_in[33];
    const float* fb  = (const float*)d_in[34];
    const float* g4  = (const float*)d_in[35];
    const float* be4 = (const float*)d_in[36];
    const float* m4  = (const float*)d_in[37];
    const float* v4  = (const float*)d_in[38];
    const float* l1w = (const float*)d_in[39];
    const float* l1b = (const float*)d_in[40];
    const float* l2w = (const float*)d_in[41];
    const float* l2b = (const float*)d_in[42];

    char* ws = (char*)d_ws;
    size_t off = 0;
    auto alloc = [&](size_t bytes) -> char* {
        char* p = ws + off;
        off += (bytes + 255) & ~(size_t)255;
        return p;
    };
    int*   deg     = (int*)alloc(NN * sizeof(int));
    int*   row_ptr = (int*)alloc((NN + 1) * sizeof(int));
    int*   cursor  = (int*)alloc(NN * sizeof(int));
    int*   bsum    = (int*)alloc(4096 * sizeof(int));
    int*   csr_src = (int*)alloc((size_t)ETOT * sizeof(int));
    float* bufA    = (float*)alloc((size_t)NN * 128 * sizeof(float));
    float* bufB    = (float*)alloc((size_t)NN * 128 * sizeof(float));
    float* bufC    = (float*)alloc((size_t)NN * 128 * sizeof(float));
    float* esrc    = (float*)alloc((size_t)NN * 2 * sizeof(float));
    float* edst    = (float*)alloc((size_t)NN * 2 * sizeof(float));
    float* pooled  = (float*)alloc((size_t)GG * 128 * sizeof(float));

    // ---- CSR build (by dst) ----
    hipMemsetAsync(deg, 0, NN * sizeof(int), stream);
    hist_kernel<<<(ETOT + 255) / 256, 256, 0, stream>>>(ei, deg);
    constexpr int NB = (NN + 255) / 256;
    scan1_kernel<<<NB, 256, 0, stream>>>(deg, row_ptr, bsum);
    scan2_kernel<<<1, 64, 0, stream>>>(bsum, NB);
    scan3_kernel<<<NB, 256, 0, stream>>>(row_ptr, bsum, cursor);
    fill_kernel<<<(ETOT + 255) / 256, 256, 0, stream>>>(ei, cursor, csr_src);

    // ---- layer 1: x[N,5] -> bufB[N,64] ----
    feat_kernel<5, 64><<<(NN + 3) / 4, 256, 0, stream>>>(
        x, w1, p1w, p1b, as1, ad1, bufA, esrc, edst, bufB, NN);
    aggregate_kernel<64><<<(NN + 3) / 4, 256, 0, stream>>>(
        bufA, (const float2*)esrc, (const float2*)edst, row_ptr, csr_src,
        b1, g1, be1, m1, v1, bufB, NN);

    // ---- layer 2: bufB[N,64] -> bufC[N,128] ----  (100000/16 = 6250 exact)
    tiled_feat_kernel<64><<<NN / 16, 256, 0, stream>>>(
        bufB, w2, p2w, p2b, as2, ad2, bufA, esrc, edst, bufC);
    aggregate_kernel<128><<<(NN + 3) / 4, 256, 0, stream>>>(
        bufA, (const float2*)esrc, (const float2*)edst, row_ptr, csr_src,
        b2, g2, be2, m2, v2, bufC, NN);

    // ---- layer 3: bufC[N,128] -> bufB[N,128] ----
    tiled_feat_kernel<128><<<NN / 16, 256, 0, stream>>>(
        bufC, w3, p3w, p3b, as3, ad3, bufA, esrc, edst, bufB);
    aggregate_kernel<128><<<(NN + 3) / 4, 256, 0, stream>>>(
        bufA, (const float2*)esrc, (const float2*)edst, row_ptr, csr_src,
        b3, g3, be3, m3, v3, bufB, NN);

    // ---- pool + head ----
    pool_kernel<<<GG, 128, 0, stream>>>(bufB, batch, pooled);
    head_kernel<<<GG, 128, 0, stream>>>(pooled, fw, fb, g4, be4, m4, v4,
                                        l1w, l1b, l2w, l2b, (float*)d_out);
}

// Round 3
// 942.837 us; speedup vs baseline: 2.0144x; 1.3400x over previous
//
#include <hip/hip_runtime.h>
#include <hip/hip_bf16.h>
#include <hip/hip_fp16.h>

#define NN   100000
#define EE   1600000
#define ETOT (EE + NN)
#define GG   256
#define BNEPS 1e-5f

// ---------------- CSR build ----------------

__global__ void hist_kernel(const int* __restrict__ ei, int* __restrict__ deg) {
    int i = blockIdx.x * blockDim.x + threadIdx.x;
    if (i >= ETOT) return;
    int dst = (i < EE) ? ei[EE + i] : (i - EE);
    atomicAdd(&deg[dst], 1);
}

__global__ void scan1_kernel(const int* __restrict__ deg, int* __restrict__ row_ptr,
                             int* __restrict__ bsum) {
    __shared__ int sdata[256];
    int i = blockIdx.x * 256 + threadIdx.x;
    int v = (i < NN) ? deg[i] : 0;
    sdata[threadIdx.x] = v;
    __syncthreads();
    int x = v;
    for (int off = 1; off < 256; off <<= 1) {
        int y = (threadIdx.x >= off) ? sdata[threadIdx.x - off] : 0;
        __syncthreads();
        x += y;
        sdata[threadIdx.x] = x;
        __syncthreads();
    }
    if (i < NN) row_ptr[i] = x - v;  // exclusive scan within block
    if (threadIdx.x == 255) bsum[blockIdx.x] = x;
}

// single-block parallel exclusive scan over block sums (NB=391 <= 512)
__global__ void scan2_kernel(int* __restrict__ bsum, int nb) {
    __shared__ int s[512];
    int t = threadIdx.x;
    int v = (t < nb) ? bsum[t] : 0;
    s[t] = v;
    __syncthreads();
    int x = v;
    for (int off = 1; off < 512; off <<= 1) {
        int y = (t >= off) ? s[t - off] : 0;
        __syncthreads();
        x += y;
        s[t] = x;
        __syncthreads();
    }
    if (t < nb) bsum[t] = x - v;
}

__global__ void scan3_kernel(int* __restrict__ row_ptr, const int* __restrict__ bsum,
                             int* __restrict__ cursor) {
    int i = blockIdx.x * 256 + threadIdx.x;
    if (i < NN) {
        int v = row_ptr[i] + bsum[blockIdx.x];
        row_ptr[i] = v;
        cursor[i] = v;
    }
    if (i == 0 && blockIdx.x == 0) row_ptr[NN] = ETOT;
}

__global__ void fill_kernel(const int* __restrict__ ei, int* __restrict__ cursor,
                            int* __restrict__ csr_src) {
    int i = blockIdx.x * blockDim.x + threadIdx.x;
    if (i >= ETOT) return;
    int src, dst;
    if (i < EE) { src = ei[i]; dst = ei[EE + i]; }
    else        { src = i - EE; dst = i - EE; }
    int pos = atomicAdd(&cursor[dst], 1);
    csr_src[pos] = src;
}

// ---------------- layer-1 feature transform (K=5, cheap); h stored fp16 ------

__global__ __launch_bounds__(256) void feat1_kernel(
    const float* __restrict__ xin, const float* __restrict__ W,
    const float* __restrict__ pw, const float* __restrict__ pb,
    const float* __restrict__ a_src, const float* __restrict__ a_dst,
    __half* __restrict__ h16, float* __restrict__ esrc, float* __restrict__ edst,
    float* __restrict__ rout, int nN)
{
    constexpr int F_IN = 5, F_OUT = 64;
    int t = threadIdx.x;
    int n = blockIdx.x * 4 + t / F_OUT;
    int f = t % F_OUT;
    if (n >= nN) return;
    float acc = 0.f, racc = 0.f;
#pragma unroll
    for (int k = 0; k < F_IN; ++k) {
        float xv = xin[n * F_IN + k];
        acc  += xv * W[k * F_OUT + f];
        racc += xv * pw[k * F_OUT + f];
    }
    h16[(size_t)n * F_OUT + f] = __float2half_rn(acc);
    rout[(size_t)n * F_OUT + f] = racc + pb[f];
    float es = acc * a_src[f];
    float ed = acc * a_dst[f];
#pragma unroll
    for (int off = 16; off > 0; off >>= 1) {
        es += __shfl_xor(es, off, 32);
        ed += __shfl_xor(ed, off, 32);
    }
    if ((t & 31) == 0) {
        int head = (f >> 5) & 1;
        esrc[n * 2 + head] = es;
        edst[n * 2 + head] = ed;
    }
}

// ---------------- register-tiled feature transform (layers 2,3; F_OUT=128) ----
// Block = 256 threads → 16 nodes × 256 output cols (h[0:128] ‖ rout[0:128]).
// h stored fp16 for the gather phase; logits/residual stay fp32.

template<int F_IN>
__global__ __launch_bounds__(256) void tiled_feat_kernel(
    const float* __restrict__ xin, const float* __restrict__ W,
    const float* __restrict__ pw, const float* __restrict__ pb,
    const float* __restrict__ a_src, const float* __restrict__ a_dst,
    __half* __restrict__ h16, float* __restrict__ esrc, float* __restrict__ edst,
    float* __restrict__ rout)
{
    constexpr int F_OUT = 128;
    constexpr int TILE_M = 16;
    constexpr int K4 = F_IN / 4;
    __shared__ float4 xs4[TILE_M * K4];

    const int tid = threadIdx.x;
    const int ft = tid & 63;
    const int nt = tid >> 6;            // 0..3
    const int base = blockIdx.x * TILE_M;

    const float4* xg = (const float4*)(xin + (size_t)base * F_IN);
    constexpr int NV = TILE_M * K4;
#pragma unroll
    for (int i = tid; i < NV; i += 256) xs4[i] = xg[i];
    __syncthreads();

    const int col4 = ft * 4;
    const bool isW = (col4 < F_OUT);
    const float* wbase = isW ? W : pw;
    const int f = isW ? col4 : (col4 - F_OUT);

    float4 acc[4];
#pragma unroll
    for (int i = 0; i < 4; ++i) acc[i] = make_float4(0.f, 0.f, 0.f, 0.f);

    for (int k0 = 0; k0 < F_IN; k0 += 4) {
        float4 w0 = *(const float4*)(wbase + (size_t)(k0 + 0) * F_OUT + f);
        float4 w1 = *(const float4*)(wbase + (size_t)(k0 + 1) * F_OUT + f);
        float4 w2 = *(const float4*)(wbase + (size_t)(k0 + 2) * F_OUT + f);
        float4 w3 = *(const float4*)(wbase + (size_t)(k0 + 3) * F_OUT + f);
        float4 xv[4];
#pragma unroll
        for (int i = 0; i < 4; ++i) xv[i] = xs4[(nt * 4 + i) * K4 + (k0 >> 2)];
#pragma unroll
        for (int i = 0; i < 4; ++i) {
            acc[i].x = fmaf(xv[i].x, w0.x, acc[i].x);
            acc[i].y = fmaf(xv[i].x, w0.y, acc[i].y);
            acc[i].z = fmaf(xv[i].x, w0.z, acc[i].z);
            acc[i].w = fmaf(xv[i].x, w0.w, acc[i].w);
            acc[i].x = fmaf(xv[i].y, w1.x, acc[i].x);
            acc[i].y = fmaf(xv[i].y, w1.y, acc[i].y);
            acc[i].z = fmaf(xv[i].y, w1.z, acc[i].z);
            acc[i].w = fmaf(xv[i].y, w1.w, acc[i].w);
            acc[i].x = fmaf(xv[i].z, w2.x, acc[i].x);
            acc[i].y = fmaf(xv[i].z, w2.y, acc[i].y);
            acc[i].z = fmaf(xv[i].z, w2.z, acc[i].z);
            acc[i].w = fmaf(xv[i].z, w2.w, acc[i].w);
            acc[i].x = fmaf(xv[i].w, w3.x, acc[i].x);
            acc[i].y = fmaf(xv[i].w, w3.y, acc[i].y);
            acc[i].z = fmaf(xv[i].w, w3.z, acc[i].z);
            acc[i].w = fmaf(xv[i].w, w3.w, acc[i].w);
        }
    }

    if (isW) {
#pragma unroll
        for (int i = 0; i < 4; ++i) {
            int node = base + nt * 4 + i;
            __half2* hp = (__half2*)(h16 + (size_t)node * F_OUT + f);
            hp[0] = __floats2half2_rn(acc[i].x, acc[i].y);
            hp[1] = __floats2half2_rn(acc[i].z, acc[i].w);
        }
        float4 av = *(const float4*)(a_src + f);
        float4 dv = *(const float4*)(a_dst + f);
#pragma unroll
        for (int i = 0; i < 4; ++i) {
            float es = acc[i].x * av.x + acc[i].y * av.y + acc[i].z * av.z + acc[i].w * av.w;
            float ed = acc[i].x * dv.x + acc[i].y * dv.y + acc[i].z * dv.z + acc[i].w * dv.w;
#pragma unroll
            for (int off = 8; off > 0; off >>= 1) {
                es += __shfl_xor(es, off, 16);
                ed += __shfl_xor(ed, off, 16);
            }
            if ((ft & 15) == 0) {
                int node = base + nt * 4 + i;
                int head = ft >> 4;   // 0 or 1
                esrc[node * 2 + head] = es;
                edst[node * 2 + head] = ed;
            }
        }
    } else {
        float4 bv = *(const float4*)(pb + f);
#pragma unroll
        for (int i = 0; i < 4; ++i) {
            int node = base + nt * 4 + i;
            float4 r = acc[i];
            r.x += bv.x; r.y += bv.y; r.z += bv.z; r.w += bv.w;
            *(float4*)(rout + (size_t)node * F_OUT + f) = r;
        }
    }
}

// ---------------- fused softmax-aggregate, F=128 (fp16 h, unroll x4) ---------
// One wave per dst node; lane handles 2 features via one __half2 gather.
// lanes 0..31 = head0 (features 0..63), lanes 32..63 = head1 (features 64..127).

__global__ __launch_bounds__(256) void aggregate128_kernel(
    const __half2* __restrict__ h2, const float2* __restrict__ esrc,
    const float2* __restrict__ edst,
    const int* __restrict__ row_ptr, const int* __restrict__ csr_src,
    const float* __restrict__ bias, const float* __restrict__ bng,
    const float* __restrict__ bnb, const float* __restrict__ bnm,
    const float* __restrict__ bnv, float* __restrict__ out, int nN)
{
    int w = threadIdx.x >> 6;
    int lane = threadIdx.x & 63;
    int n = blockIdx.x * 4 + w;
    if (n >= nN) return;
    float2 edv = edst[n];
    bool hi = lane >= 32;
    float ed = hi ? edv.y : edv.x;
    int jb = row_ptr[n], je = row_ptr[n + 1];
    float s = 0.f, ax = 0.f, ay = 0.f;
    int j = jb;
    for (; j + 4 <= je; j += 4) {
        int i0 = csr_src[j + 0], i1 = csr_src[j + 1];
        int i2 = csr_src[j + 2], i3 = csr_src[j + 3];
        float2 q0 = esrc[i0], q1 = esrc[i1], q2 = esrc[i2], q3 = esrc[i3];
        __half2 v0 = h2[(size_t)i0 * 64 + lane];
        __half2 v1 = h2[(size_t)i1 * 64 + lane];
        __half2 v2 = h2[(size_t)i2 * 64 + lane];
        __half2 v3 = h2[(size_t)i3 * 64 + lane];
        float a0 = (hi ? q0.y : q0.x) + ed; a0 = (a0 > 0.f) ? a0 : 0.2f * a0;
        float a1 = (hi ? q1.y : q1.x) + ed; a1 = (a1 > 0.f) ? a1 : 0.2f * a1;
        float a2 = (hi ? q2.y : q2.x) + ed; a2 = (a2 > 0.f) ? a2 : 0.2f * a2;
        float a3 = (hi ? q3.y : q3.x) + ed; a3 = (a3 > 0.f) ? a3 : 0.2f * a3;
        float w0 = __expf(a0), w1 = __expf(a1), w2 = __expf(a2), w3 = __expf(a3);
        float2 f0 = __half22float2(v0), f1 = __half22float2(v1);
        float2 f2 = __half22float2(v2), f3 = __half22float2(v3);
        ax = fmaf(w0, f0.x, ax); ay = fmaf(w0, f0.y, ay);
        ax = fmaf(w1, f1.x, ax); ay = fmaf(w1, f1.y, ay);
        ax = fmaf(w2, f2.x, ax); ay = fmaf(w2, f2.y, ay);
        ax = fmaf(w3, f3.x, ax); ay = fmaf(w3, f3.y, ay);
        s += (w0 + w1) + (w2 + w3);
    }
    for (; j < je; ++j) {
        int i0 = csr_src[j];
        float2 q0 = esrc[i0];
        __half2 v0 = h2[(size_t)i0 * 64 + lane];
        float a0 = (hi ? q0.y : q0.x) + ed; a0 = (a0 > 0.f) ? a0 : 0.2f * a0;
        float w0 = __expf(a0);
        float2 f0 = __half22float2(v0);
        ax = fmaf(w0, f0.x, ax); ay = fmaf(w0, f0.y, ay);
        s += w0;
    }
    float inv = 1.f / (s + 1e-16f);
    int f0i = 2 * lane, f1i = 2 * lane + 1;
    float g0 = ax * inv, g1 = ay * inv;
    float o0 = bng[f0i] * (g0 + bias[f0i] - bnm[f0i]) * rsqrtf(bnv[f0i] + BNEPS) + bnb[f0i];
    float o1 = bng[f1i] * (g1 + bias[f1i] - bnm[f1i]) * rsqrtf(bnv[f1i] + BNEPS) + bnb[f1i];
    float2* op = (float2*)(out + (size_t)n * 128) + lane;
    float2 prev = *op;
    prev.x += fmaxf(o0, 0.f);
    prev.y += fmaxf(o1, 0.f);
    *op = prev;
}

// ---------------- fused softmax-aggregate, F=64 (fp16 h, unroll x4) ----------
// lane = feature; lanes 0..31 head0, 32..63 head1.

__global__ __launch_bounds__(256) void aggregate64_kernel(
    const __half* __restrict__ h16, const float2* __restrict__ esrc,
    const float2* __restrict__ edst,
    const int* __restrict__ row_ptr, const int* __restrict__ csr_src,
    const float* __restrict__ bias, const float* __restrict__ bng,
    const float* __restrict__ bnb, const float* __restrict__ bnm,
    const float* __restrict__ bnv, float* __restrict__ out, int nN)
{
    int w = threadIdx.x >> 6;
    int lane = threadIdx.x & 63;
    int n = blockIdx.x * 4 + w;
    if (n >= nN) return;
    float2 edv = edst[n];
    bool hi = lane >= 32;
    float ed = hi ? edv.y : edv.x;
    int jb = row_ptr[n], je = row_ptr[n + 1];
    float s = 0.f, acc = 0.f;
    int j = jb;
    for (; j + 4 <= je; j += 4) {
        int i0 = csr_src[j + 0], i1 = csr_src[j + 1];
        int i2 = csr_src[j + 2], i3 = csr_src[j + 3];
        float2 q0 = esrc[i0], q1 = esrc[i1], q2 = esrc[i2], q3 = esrc[i3];
        float v0 = __half2float(h16[(size_t)i0 * 64 + lane]);
        float v1 = __half2float(h16[(size_t)i1 * 64 + lane]);
        float v2 = __half2float(h16[(size_t)i2 * 64 + lane]);
        float v3 = __half2float(h16[(size_t)i3 * 64 + lane]);
        float a0 = (hi ? q0.y : q0.x) + ed; a0 = (a0 > 0.f) ? a0 : 0.2f * a0;
        float a1 = (hi ? q1.y : q1.x) + ed; a1 = (a1 > 0.f) ? a1 : 0.2f * a1;
        float a2 = (hi ? q2.y : q2.x) + ed; a2 = (a2 > 0.f) ? a2 : 0.2f * a2;
        float a3 = (hi ? q3.y : q3.x) + ed; a3 = (a3 > 0.f) ? a3 : 0.2f * a3;
        float w0 = __expf(a0), w1 = __expf(a1), w2 = __expf(a2), w3 = __expf(a3);
        acc = fmaf(w0, v0, acc);
        acc = fmaf(w1, v1, acc);
        acc = fmaf(w2, v2, acc);
        acc = fmaf(w3, v3, acc);
        s += (w0 + w1) + (w2 + w3);
    }
    for (; j < je; ++j) {
        int i0 = csr_src[j];
        float2 q0 = esrc[i0];
        float v0 = __half2float(h16[(size_t)i0 * 64 + lane]);
        float a0 = (hi ? q0.y : q0.x) + ed; a0 = (a0 > 0.f) ? a0 : 0.2f * a0;
        float w0 = __expf(a0);
        acc = fmaf(w0, v0, acc);
        s += w0;
    }
    int f = lane;
    float g = acc / (s + 1e-16f);
    float v = bng[f] * (g + bias[f] - bnm[f]) * rsqrtf(bnv[f] + BNEPS) + bnb[f];
    out[(size_t)n * 64 + f] = fmaxf(v, 0.f) + out[(size_t)n * 64 + f];
}

// ---------------- pooling (segment mean over sorted batch) ----------------

__global__ __launch_bounds__(128) void pool_kernel(const float* __restrict__ hfin,
                                                   const int* __restrict__ batch,
                                                   float* __restrict__ pooled) {
    int g = blockIdx.x;
    int f = threadIdx.x;
    int lo = 0, hi = NN;
    while (lo < hi) { int mid = (lo + hi) >> 1; if (batch[mid] < g) lo = mid + 1; else hi = mid; }
    int start = lo;
    hi = NN;
    while (lo < hi) { int mid = (lo + hi) >> 1; if (batch[mid] < g + 1) lo = mid + 1; else hi = mid; }
    int end = lo;
    float acc = 0.f;
    for (int i = start; i < end; ++i) acc += hfin[(size_t)i * 128 + f];
    float cnt = (float)(end - start);
    pooled[g * 128 + f] = acc / fmaxf(cnt, 1.0f);
}

// ---------------- MLP head ----------------

__global__ __launch_bounds__(128) void head_kernel(
    const float* __restrict__ pooled, const float* __restrict__ fw, const float* __restrict__ fb,
    const float* __restrict__ g4, const float* __restrict__ be4,
    const float* __restrict__ m4, const float* __restrict__ v4,
    const float* __restrict__ l1w, const float* __restrict__ l1b,
    const float* __restrict__ l2w, const float* __restrict__ l2b,
    float* __restrict__ out)
{
    __shared__ float p[128];
    __shared__ float z1[32];
    __shared__ float z2[32];
    int g = blockIdx.x, t = threadIdx.x;
    p[t] = pooled[g * 128 + t];
    __syncthreads();
    if (t < 32) {
        float acc = fb[t];
        for (int k = 0; k < 128; ++k) acc += p[k] * fw[k * 32 + t];
        float val = g4[t] * (acc - m4[t]) * rsqrtf(v4[t] + BNEPS) + be4[t];
        z1[t] = fmaxf(val, 0.f);
    }
    __syncthreads();
    if (t < 32) {
        float acc = l1b[t];
        for (int k = 0; k < 32; ++k) acc += z1[k] * l1w[k * 32 + t];
        z2[t] = fmaxf(acc, 0.f);
    }
    __syncthreads();
    if (t < 10) {
        float acc = l2b[t];
        for (int k = 0; k < 32; ++k) acc += z2[k] * l2w[k * 10 + t];
        out[g * 10 + t] = acc;
    }
}

// ---------------- launch ----------------

extern "C" void kernel_launch(void* const* d_in, const int* in_sizes, int n_in,
                              void* d_out, int out_size, void* d_ws, size_t ws_size,
                              hipStream_t stream) {
    const float* x     = (const float*)d_in[0];
    const int*   ei    = (const int*)d_in[1];
    const int*   batch = (const int*)d_in[2];
    const float* w1  = (const float*)d_in[3];
    const float* as1 = (const float*)d_in[4];
    const float* ad1 = (const float*)d_in[5];
    const float* b1  = (const float*)d_in[6];
    const float* g1  = (const float*)d_in[7];
    const float* be1 = (const float*)d_in[8];
    const float* m1  = (const float*)d_in[9];
    const float* v1  = (const float*)d_in[10];
    const float* p1w = (const float*)d_in[11];
    const float* p1b = (const float*)d_in[12];
    const float* w2  = (const float*)d_in[13];
    const float* as2 = (const float*)d_in[14];
    const float* ad2 = (const float*)d_in[15];
    const float* b2  = (const float*)d_in[16];
    const float* g2  = (const float*)d_in[17];
    const float* be2 = (const float*)d_in[18];
    const float* m2  = (const float*)d_in[19];
    const float* v2  = (const float*)d_in[20];
    const float* p2w = (const float*)d_in[21];
    const float* p2b = (const float*)d_in[22];
    const float* w3  = (const float*)d_in[23];
    const float* as3 = (const float*)d_in[24];
    const float* ad3 = (const float*)d_in[25];
    const float* b3  = (const float*)d_in[26];
    const float* g3  = (const float*)d_in[27];
    const float* be3 = (const float*)d_in[28];
    const float* m3  = (const float*)d_in[29];
    const float* v3  = (const float*)d_in[30];
    const float* p3w = (const float*)d_in[31];
    const float* p3b = (const float*)d_in[32];
    const float* fw  = (const float*)d_in[33];
    const float* fb  = (const float*)d_in[34];
    const float* g4  = (const float*)d_in[35];
    const float* be4 = (const float*)d_in[36];
    const float* m4  = (const float*)d_in[37];
    const float* v4  = (const float*)d_in[38];
    const float* l1w = (const float*)d_in[39];
    const float* l1b = (const float*)d_in[40];
    const float* l2w = (const float*)d_in[41];
    const float* l2b = (const float*)d_in[42];

    char* ws = (char*)d_ws;
    size_t off = 0;
    auto alloc = [&](size_t bytes) -> char* {
        char* p = ws + off;
        off += (bytes + 255) & ~(size_t)255;
        return p;
    };
    int*    deg     = (int*)alloc(NN * sizeof(int));
    int*    row_ptr = (int*)alloc((NN + 1) * sizeof(int));
    int*    cursor  = (int*)alloc(NN * sizeof(int));
    int*    bsum    = (int*)alloc(4096 * sizeof(int));
    int*    csr_src = (int*)alloc((size_t)ETOT * sizeof(int));
    __half* h16     = (__half*)alloc((size_t)NN * 128 * sizeof(__half));
    float*  bufB    = (float*)alloc((size_t)NN * 128 * sizeof(float));
    float*  bufC    = (float*)alloc((size_t)NN * 128 * sizeof(float));
    float*  esrc    = (float*)alloc((size_t)NN * 2 * sizeof(float));
    float*  edst    = (float*)alloc((size_t)NN * 2 * sizeof(float));
    float*  pooled  = (float*)alloc((size_t)GG * 128 * sizeof(float));

    // ---- CSR build (by dst) ----
    hipMemsetAsync(deg, 0, NN * sizeof(int), stream);
    hist_kernel<<<(ETOT + 255) / 256, 256, 0, stream>>>(ei, deg);
    constexpr int NB = (NN + 255) / 256;
    scan1_kernel<<<NB, 256, 0, stream>>>(deg, row_ptr, bsum);
    scan2_kernel<<<1, 512, 0, stream>>>(bsum, NB);
    scan3_kernel<<<NB, 256, 0, stream>>>(row_ptr, bsum, cursor);
    fill_kernel<<<(ETOT + 255) / 256, 256, 0, stream>>>(ei, cursor, csr_src);

    // ---- layer 1: x[N,5] -> bufB[N,64] ----
    feat1_kernel<<<(NN + 3) / 4, 256, 0, stream>>>(
        x, w1, p1w, p1b, as1, ad1, h16, esrc, edst, bufB, NN);
    aggregate64_kernel<<<(NN + 3) / 4, 256, 0, stream>>>(
        h16, (const float2*)esrc, (const float2*)edst, row_ptr, csr_src,
        b1, g1, be1, m1, v1, bufB, NN);

    // ---- layer 2: bufB[N,64] -> bufC[N,128] ----
    tiled_feat_kernel<64><<<NN / 16, 256, 0, stream>>>(
        bufB, w2, p2w, p2b, as2, ad2, h16, esrc, edst, bufC);
    aggregate128_kernel<<<(NN + 3) / 4, 256, 0, stream>>>(
        (const __half2*)h16, (const float2*)esrc, (const float2*)edst, row_ptr, csr_src,
        b2, g2, be2, m2, v2, bufC, NN);

    // ---- layer 3: bufC[N,128] -> bufB[N,128] ----
    tiled_feat_kernel<128><<<NN / 16, 256, 0, stream>>>(
        bufC, w3, p3w, p3b, as3, ad3, h16, esrc, edst, bufB);
    aggregate128_kernel<<<(NN + 3) / 4, 256, 0, stream>>>(
        (const __half2*)h16, (const float2*)esrc, (const float2*)edst, row_ptr, csr_src,
        b3, g3, be3, m3, v3, bufB, NN);

    // ---- pool + head ----
    pool_kernel<<<GG, 128, 0, stream>>>(bufB, batch, pooled);
    head_kernel<<<GG, 128, 0, stream>>>(pooled, fw, fb, g4, be4, m4, v4,
                                        l1w, l1b, l2w, l2b, (float*)d_out);
}

// Round 4
// 822.641 us; speedup vs baseline: 2.3087x; 1.1461x over previous
//
#include <hip/hip_runtime.h>
#include <hip/hip_bf16.h>
#include <hip/hip_fp16.h>

#define NN   100000
#define EE   1600000
#define ETOT (EE + NN)
#define GG   256
#define BNEPS 1e-5f
#define NBK  391          // buckets of 256 nodes: (NN+255)/256

// ---------------- CSR build: bucketed partition (single-writer cache lines) --

// Phase A1: global bucket histogram via per-block LDS aggregation.
__global__ __launch_bounds__(256) void bucket_count_kernel(
    const int* __restrict__ ei, int* __restrict__ bucket_cnt)
{
    __shared__ int cnt[NBK];
    for (int i = threadIdx.x; i < NBK; i += 256) cnt[i] = 0;
    __syncthreads();
    int base = blockIdx.x * 8192;
    for (int k = threadIdx.x; k < 8192; k += 256) {
        int e = base + k;
        if (e < ETOT) {
            int dst = (e < EE) ? ei[EE + e] : (e - EE);
            atomicAdd(&cnt[dst >> 8], 1);
        }
    }
    __syncthreads();
    for (int i = threadIdx.x; i < NBK; i += 256)
        if (cnt[i]) atomicAdd(&bucket_cnt[i], cnt[i]);
}

// Phase A-scan: exclusive scan over 391 bucket counts (single block).
__global__ __launch_bounds__(512) void bucket_scan_kernel(
    const int* __restrict__ bucket_cnt, int* __restrict__ bucket_base,
    int* __restrict__ gcursor)
{
    __shared__ int s[512];
    int t = threadIdx.x;
    int v = (t < NBK) ? bucket_cnt[t] : 0;
    s[t] = v;
    __syncthreads();
    int x = v;
    for (int o = 1; o < 512; o <<= 1) {
        int y = (t >= o) ? s[t - o] : 0;
        __syncthreads();
        x += y;
        s[t] = x;
        __syncthreads();
    }
    if (t < NBK) { bucket_base[t] = x - v; gcursor[t] = x - v; }
    if (t == 0) bucket_base[NBK] = ETOT;
}

// Phase A2: partition edges into bucket-ordered array. Each block claims
// per-bucket runs (one atomic per bucket per block) so global writes are
// short contiguous runs with a single writing block per line (mostly).
// Packed entry: src (17 bits) | dstLocal (8 bits) << 17.
__global__ __launch_bounds__(256) void partition_kernel(
    const int* __restrict__ ei, int* __restrict__ gcursor, int* __restrict__ part)
{
    __shared__ int cnt[NBK];
    __shared__ int basel[NBK];
    for (int i = threadIdx.x; i < NBK; i += 256) cnt[i] = 0;
    __syncthreads();
    int base = blockIdx.x * 4096;
    // pass 1: count chunk
    for (int k = threadIdx.x; k < 4096; k += 256) {
        int e = base + k;
        if (e < ETOT) {
            int dst = (e < EE) ? ei[EE + e] : (e - EE);
            atomicAdd(&cnt[dst >> 8], 1);
        }
    }
    __syncthreads();
    // claim global runs
    for (int i = threadIdx.x; i < NBK; i += 256) {
        int c = cnt[i];
        basel[i] = c ? atomicAdd(&gcursor[i], c) : 0;
        cnt[i] = 0;   // reuse as intra-block cursor
    }
    __syncthreads();
    // pass 2: scatter into claimed runs
    for (int k = threadIdx.x; k < 4096; k += 256) {
        int e = base + k;
        if (e < ETOT) {
            int src, dst;
            if (e < EE) { src = ei[e]; dst = ei[EE + e]; }
            else        { src = e - EE; dst = e - EE; }
            int b = dst >> 8;
            int slot = atomicAdd(&cnt[b], 1);
            part[basel[b] + slot] = src | ((dst & 255) << 17);
        }
    }
}

// Phase B: per-bucket CSR build. One block per bucket; all scattered writes
// stay within the block's own csr slice (~17 KB) → single-XCD locality.
__global__ __launch_bounds__(256) void csr_build_kernel(
    const int* __restrict__ part, const int* __restrict__ bucket_base,
    int* __restrict__ row_ptr, int* __restrict__ csr_src)
{
    __shared__ int deg[256];
    __shared__ int sc[256];
    int b = blockIdx.x;
    int t = threadIdx.x;
    int beg = bucket_base[b], end = bucket_base[b + 1];
    deg[t] = 0;
    __syncthreads();
    for (int j = beg + t; j < end; j += 256)
        atomicAdd(&deg[(part[j] >> 17) & 255], 1);
    __syncthreads();
    int v = deg[t];
    sc[t] = v;
    __syncthreads();
    int x = v;
    for (int o = 1; o < 256; o <<= 1) {
        int y = (t >= o) ? sc[t - o] : 0;
        __syncthreads();
        x += y;
        sc[t] = x;
        __syncthreads();
    }
    int excl = x - v;
    int node = b * 256 + t;
    if (node < NN) row_ptr[node] = beg + excl;
    __syncthreads();
    deg[t] = beg + excl;   // per-node global cursor
    __syncthreads();
    for (int j = beg + t; j < end; j += 256) {
        int pv = part[j];
        int pos = atomicAdd(&deg[(pv >> 17) & 255], 1);
        csr_src[pos] = pv & 0x1FFFF;
    }
    if (b == 0 && t == 0) row_ptr[NN] = ETOT;
}

// ---------------- layer-1 feature transform (K=5, cheap); h stored fp16 ------

__global__ __launch_bounds__(256) void feat1_kernel(
    const float* __restrict__ xin, const float* __restrict__ W,
    const float* __restrict__ pw, const float* __restrict__ pb,
    const float* __restrict__ a_src, const float* __restrict__ a_dst,
    __half* __restrict__ h16, float* __restrict__ esrc, float* __restrict__ edst,
    float* __restrict__ rout, int nN)
{
    constexpr int F_IN = 5, F_OUT = 64;
    int t = threadIdx.x;
    int n = blockIdx.x * 4 + t / F_OUT;
    int f = t % F_OUT;
    if (n >= nN) return;
    float acc = 0.f, racc = 0.f;
#pragma unroll
    for (int k = 0; k < F_IN; ++k) {
        float xv = xin[n * F_IN + k];
        acc  += xv * W[k * F_OUT + f];
        racc += xv * pw[k * F_OUT + f];
    }
    h16[(size_t)n * F_OUT + f] = __float2half_rn(acc);
    rout[(size_t)n * F_OUT + f] = racc + pb[f];
    float es = acc * a_src[f];
    float ed = acc * a_dst[f];
#pragma unroll
    for (int off = 16; off > 0; off >>= 1) {
        es += __shfl_xor(es, off, 32);
        ed += __shfl_xor(ed, off, 32);
    }
    if ((t & 31) == 0) {
        int head = (f >> 5) & 1;
        esrc[n * 2 + head] = es;
        edst[n * 2 + head] = ed;
    }
}

// ---------------- register-tiled feature transform (layers 2,3; F_OUT=128) ----

template<int F_IN>
__global__ __launch_bounds__(256) void tiled_feat_kernel(
    const float* __restrict__ xin, const float* __restrict__ W,
    const float* __restrict__ pw, const float* __restrict__ pb,
    const float* __restrict__ a_src, const float* __restrict__ a_dst,
    __half* __restrict__ h16, float* __restrict__ esrc, float* __restrict__ edst,
    float* __restrict__ rout)
{
    constexpr int F_OUT = 128;
    constexpr int TILE_M = 16;
    constexpr int K4 = F_IN / 4;
    __shared__ float4 xs4[TILE_M * K4];

    const int tid = threadIdx.x;
    const int ft = tid & 63;
    const int nt = tid >> 6;            // 0..3
    const int base = blockIdx.x * TILE_M;

    const float4* xg = (const float4*)(xin + (size_t)base * F_IN);
    constexpr int NV = TILE_M * K4;
#pragma unroll
    for (int i = tid; i < NV; i += 256) xs4[i] = xg[i];
    __syncthreads();

    const int col4 = ft * 4;
    const bool isW = (col4 < F_OUT);
    const float* wbase = isW ? W : pw;
    const int f = isW ? col4 : (col4 - F_OUT);

    float4 acc[4];
#pragma unroll
    for (int i = 0; i < 4; ++i) acc[i] = make_float4(0.f, 0.f, 0.f, 0.f);

    for (int k0 = 0; k0 < F_IN; k0 += 4) {
        float4 w0 = *(const float4*)(wbase + (size_t)(k0 + 0) * F_OUT + f);
        float4 w1 = *(const float4*)(wbase + (size_t)(k0 + 1) * F_OUT + f);
        float4 w2 = *(const float4*)(wbase + (size_t)(k0 + 2) * F_OUT + f);
        float4 w3 = *(const float4*)(wbase + (size_t)(k0 + 3) * F_OUT + f);
        float4 xv[4];
#pragma unroll
        for (int i = 0; i < 4; ++i) xv[i] = xs4[(nt * 4 + i) * K4 + (k0 >> 2)];
#pragma unroll
        for (int i = 0; i < 4; ++i) {
            acc[i].x = fmaf(xv[i].x, w0.x, acc[i].x);
            acc[i].y = fmaf(xv[i].x, w0.y, acc[i].y);
            acc[i].z = fmaf(xv[i].x, w0.z, acc[i].z);
            acc[i].w = fmaf(xv[i].x, w0.w, acc[i].w);
            acc[i].x = fmaf(xv[i].y, w1.x, acc[i].x);
            acc[i].y = fmaf(xv[i].y, w1.y, acc[i].y);
            acc[i].z = fmaf(xv[i].y, w1.z, acc[i].z);
            acc[i].w = fmaf(xv[i].y, w1.w, acc[i].w);
            acc[i].x = fmaf(xv[i].z, w2.x, acc[i].x);
            acc[i].y = fmaf(xv[i].z, w2.y, acc[i].y);
            acc[i].z = fmaf(xv[i].z, w2.z, acc[i].z);
            acc[i].w = fmaf(xv[i].z, w2.w, acc[i].w);
            acc[i].x = fmaf(xv[i].w, w3.x, acc[i].x);
            acc[i].y = fmaf(xv[i].w, w3.y, acc[i].y);
            acc[i].z = fmaf(xv[i].w, w3.z, acc[i].z);
            acc[i].w = fmaf(xv[i].w, w3.w, acc[i].w);
        }
    }

    if (isW) {
#pragma unroll
        for (int i = 0; i < 4; ++i) {
            int node = base + nt * 4 + i;
            __half2* hp = (__half2*)(h16 + (size_t)node * F_OUT + f);
            hp[0] = __floats2half2_rn(acc[i].x, acc[i].y);
            hp[1] = __floats2half2_rn(acc[i].z, acc[i].w);
        }
        float4 av = *(const float4*)(a_src + f);
        float4 dv = *(const float4*)(a_dst + f);
#pragma unroll
        for (int i = 0; i < 4; ++i) {
            float es = acc[i].x * av.x + acc[i].y * av.y + acc[i].z * av.z + acc[i].w * av.w;
            float ed = acc[i].x * dv.x + acc[i].y * dv.y + acc[i].z * dv.z + acc[i].w * dv.w;
#pragma unroll
            for (int off = 8; off > 0; off >>= 1) {
                es += __shfl_xor(es, off, 16);
                ed += __shfl_xor(ed, off, 16);
            }
            if ((ft & 15) == 0) {
                int node = base + nt * 4 + i;
                int head = ft >> 4;   // 0 or 1
                esrc[node * 2 + head] = es;
                edst[node * 2 + head] = ed;
            }
        }
    } else {
        float4 bv = *(const float4*)(pb + f);
#pragma unroll
        for (int i = 0; i < 4; ++i) {
            int node = base + nt * 4 + i;
            float4 r = acc[i];
            r.x += bv.x; r.y += bv.y; r.z += bv.z; r.w += bv.w;
            *(float4*)(rout + (size_t)node * F_OUT + f) = r;
        }
    }
}

// ---------------- fused softmax-aggregate, F=128 (fp16 h, unroll x8) ---------

__global__ __launch_bounds__(256) void aggregate128_kernel(
    const __half2* __restrict__ h2, const float2* __restrict__ esrc,
    const float2* __restrict__ edst,
    const int* __restrict__ row_ptr, const int* __restrict__ csr_src,
    const float* __restrict__ bias, const float* __restrict__ bng,
    const float* __restrict__ bnb, const float* __restrict__ bnm,
    const float* __restrict__ bnv, float* __restrict__ out, int nN)
{
    int w = threadIdx.x >> 6;
    int lane = threadIdx.x & 63;
    int n = blockIdx.x * 4 + w;
    if (n >= nN) return;
    float2 edv = edst[n];
    bool hi = lane >= 32;
    float ed = hi ? edv.y : edv.x;
    int jb = row_ptr[n], je = row_ptr[n + 1];
    float s = 0.f, ax = 0.f, ay = 0.f;
    int j = jb;
    for (; j + 8 <= je; j += 8) {
        int idx[8];
#pragma unroll
        for (int u = 0; u < 8; ++u) idx[u] = csr_src[j + u];
        float2 q[8];
        __half2 v[8];
#pragma unroll
        for (int u = 0; u < 8; ++u) {
            q[u] = esrc[idx[u]];
            v[u] = h2[(size_t)idx[u] * 64 + lane];
        }
#pragma unroll
        for (int u = 0; u < 8; ++u) {
            float a = (hi ? q[u].y : q[u].x) + ed;
            a = (a > 0.f) ? a : 0.2f * a;
            float wgt = __expf(a);
            float2 f = __half22float2(v[u]);
            ax = fmaf(wgt, f.x, ax);
            ay = fmaf(wgt, f.y, ay);
            s += wgt;
        }
    }
    for (; j < je; ++j) {
        int i0 = csr_src[j];
        float2 q0 = esrc[i0];
        __half2 v0 = h2[(size_t)i0 * 64 + lane];
        float a0 = (hi ? q0.y : q0.x) + ed;
        a0 = (a0 > 0.f) ? a0 : 0.2f * a0;
        float w0 = __expf(a0);
        float2 f0 = __half22float2(v0);
        ax = fmaf(w0, f0.x, ax);
        ay = fmaf(w0, f0.y, ay);
        s += w0;
    }
    float inv = 1.f / (s + 1e-16f);
    int f0i = 2 * lane, f1i = 2 * lane + 1;
    float g0 = ax * inv, g1 = ay * inv;
    float o0 = bng[f0i] * (g0 + bias[f0i] - bnm[f0i]) * rsqrtf(bnv[f0i] + BNEPS) + bnb[f0i];
    float o1 = bng[f1i] * (g1 + bias[f1i] - bnm[f1i]) * rsqrtf(bnv[f1i] + BNEPS) + bnb[f1i];
    float2* op = (float2*)(out + (size_t)n * 128) + lane;
    float2 prev = *op;
    prev.x += fmaxf(o0, 0.f);
    prev.y += fmaxf(o1, 0.f);
    *op = prev;
}

// ---------------- fused softmax-aggregate, F=64 (fp16 h, unroll x8) ----------

__global__ __launch_bounds__(256) void aggregate64_kernel(
    const __half* __restrict__ h16, const float2* __restrict__ esrc,
    const float2* __restrict__ edst,
    const int* __restrict__ row_ptr, const int* __restrict__ csr_src,
    const float* __restrict__ bias, const float* __restrict__ bng,
    const float* __restrict__ bnb, const float* __restrict__ bnm,
    const float* __restrict__ bnv, float* __restrict__ out, int nN)
{
    int w = threadIdx.x >> 6;
    int lane = threadIdx.x & 63;
    int n = blockIdx.x * 4 + w;
    if (n >= nN) return;
    float2 edv = edst[n];
    bool hi = lane >= 32;
    float ed = hi ? edv.y : edv.x;
    int jb = row_ptr[n], je = row_ptr[n + 1];
    float s = 0.f, acc = 0.f;
    int j = jb;
    for (; j + 8 <= je; j += 8) {
        int idx[8];
#pragma unroll
        for (int u = 0; u < 8; ++u) idx[u] = csr_src[j + u];
        float2 q[8];
        float v[8];
#pragma unroll
        for (int u = 0; u < 8; ++u) {
            q[u] = esrc[idx[u]];
            v[u] = __half2float(h16[(size_t)idx[u] * 64 + lane]);
        }
#pragma unroll
        for (int u = 0; u < 8; ++u) {
            float a = (hi ? q[u].y : q[u].x) + ed;
            a = (a > 0.f) ? a : 0.2f * a;
            float wgt = __expf(a);
            acc = fmaf(wgt, v[u], acc);
            s += wgt;
        }
    }
    for (; j < je; ++j) {
        int i0 = csr_src[j];
        float2 q0 = esrc[i0];
        float v0 = __half2float(h16[(size_t)i0 * 64 + lane]);
        float a0 = (hi ? q0.y : q0.x) + ed;
        a0 = (a0 > 0.f) ? a0 : 0.2f * a0;
        float w0 = __expf(a0);
        acc = fmaf(w0, v0, acc);
        s += w0;
    }
    int f = lane;
    float g = acc / (s + 1e-16f);
    float v = bng[f] * (g + bias[f] - bnm[f]) * rsqrtf(bnv[f] + BNEPS) + bnb[f];
    out[(size_t)n * 64 + f] = fmaxf(v, 0.f) + out[(size_t)n * 64 + f];
}

// ---------------- pooling (segment mean over sorted batch) ----------------

__global__ __launch_bounds__(128) void pool_kernel(const float* __restrict__ hfin,
                                                   const int* __restrict__ batch,
                                                   float* __restrict__ pooled) {
    int g = blockIdx.x;
    int f = threadIdx.x;
    int lo = 0, hi = NN;
    while (lo < hi) { int mid = (lo + hi) >> 1; if (batch[mid] < g) lo = mid + 1; else hi = mid; }
    int start = lo;
    hi = NN;
    while (lo < hi) { int mid = (lo + hi) >> 1; if (batch[mid] < g + 1) lo = mid + 1; else hi = mid; }
    int end = lo;
    float acc = 0.f;
    for (int i = start; i < end; ++i) acc += hfin[(size_t)i * 128 + f];
    float cnt = (float)(end - start);
    pooled[g * 128 + f] = acc / fmaxf(cnt, 1.0f);
}

// ---------------- MLP head ----------------

__global__ __launch_bounds__(128) void head_kernel(
    const float* __restrict__ pooled, const float* __restrict__ fw, const float* __restrict__ fb,
    const float* __restrict__ g4, const float* __restrict__ be4,
    const float* __restrict__ m4, const float* __restrict__ v4,
    const float* __restrict__ l1w, const float* __restrict__ l1b,
    const float* __restrict__ l2w, const float* __restrict__ l2b,
    float* __restrict__ out)
{
    __shared__ float p[128];
    __shared__ float z1[32];
    __shared__ float z2[32];
    int g = blockIdx.x, t = threadIdx.x;
    p[t] = pooled[g * 128 + t];
    __syncthreads();
    if (t < 32) {
        float acc = fb[t];
        for (int k = 0; k < 128; ++k) acc += p[k] * fw[k * 32 + t];
        float val = g4[t] * (acc - m4[t]) * rsqrtf(v4[t] + BNEPS) + be4[t];
        z1[t] = fmaxf(val, 0.f);
    }
    __syncthreads();
    if (t < 32) {
        float acc = l1b[t];
        for (int k = 0; k < 32; ++k) acc += z1[k] * l1w[k * 32 + t];
        z2[t] = fmaxf(acc, 0.f);
    }
    __syncthreads();
    if (t < 10) {
        float acc = l2b[t];
        for (int k = 0; k < 32; ++k) acc += z2[k] * l2w[k * 10 + t];
        out[g * 10 + t] = acc;
    }
}

// ---------------- launch ----------------

extern "C" void kernel_launch(void* const* d_in, const int* in_sizes, int n_in,
                              void* d_out, int out_size, void* d_ws, size_t ws_size,
                              hipStream_t stream) {
    const float* x     = (const float*)d_in[0];
    const int*   ei    = (const int*)d_in[1];
    const int*   batch = (const int*)d_in[2];
    const float* w1  = (const float*)d_in[3];
    const float* as1 = (const float*)d_in[4];
    const float* ad1 = (const float*)d_in[5];
    const float* b1  = (const float*)d_in[6];
    const float* g1  = (const float*)d_in[7];
    const float* be1 = (const float*)d_in[8];
    const float* m1  = (const float*)d_in[9];
    const float* v1  = (const float*)d_in[10];
    const float* p1w = (const float*)d_in[11];
    const float* p1b = (const float*)d_in[12];
    const float* w2  = (const float*)d_in[13];
    const float* as2 = (const float*)d_in[14];
    const float* ad2 = (const float*)d_in[15];
    const float* b2  = (const float*)d_in[16];
    const float* g2  = (const float*)d_in[17];
    const float* be2 = (const float*)d_in[18];
    const float* m2  = (const float*)d_in[19];
    const float* v2  = (const float*)d_in[20];
    const float* p2w = (const float*)d_in[21];
    const float* p2b = (const float*)d_in[22];
    const float* w3  = (const float*)d_in[23];
    const float* as3 = (const float*)d_in[24];
    const float* ad3 = (const float*)d_in[25];
    const float* b3  = (const float*)d_in[26];
    const float* g3  = (const float*)d_in[27];
    const float* be3 = (const float*)d_in[28];
    const float* m3  = (const float*)d_in[29];
    const float* v3  = (const float*)d_in[30];
    const float* p3w = (const float*)d_in[31];
    const float* p3b = (const float*)d_in[32];
    const float* fw  = (const float*)d_in[33];
    const float* fb  = (const float*)d_in[34];
    const float* g4  = (const float*)d_in[35];
    const float* be4 = (const float*)d_in[36];
    const float* m4  = (const float*)d_in[37];
    const float* v4  = (const float*)d_in[38];
    const float* l1w = (const float*)d_in[39];
    const float* l1b = (const float*)d_in[40];
    const float* l2w = (const float*)d_in[41];
    const float* l2b = (const float*)d_in[42];

    char* ws = (char*)d_ws;
    size_t off = 0;
    auto alloc = [&](size_t bytes) -> char* {
        char* p = ws + off;
        off += (bytes + 255) & ~(size_t)255;
        return p;
    };
    int*    bucket_cnt  = (int*)alloc((NBK) * sizeof(int));
    int*    bucket_base = (int*)alloc((NBK + 1) * sizeof(int));
    int*    gcursor     = (int*)alloc((NBK) * sizeof(int));
    int*    part        = (int*)alloc((size_t)ETOT * sizeof(int));
    int*    row_ptr     = (int*)alloc((NN + 1) * sizeof(int));
    int*    csr_src     = (int*)alloc((size_t)ETOT * sizeof(int));
    __half* h16         = (__half*)alloc((size_t)NN * 128 * sizeof(__half));
    float*  bufB        = (float*)alloc((size_t)NN * 128 * sizeof(float));
    float*  bufC        = (float*)alloc((size_t)NN * 128 * sizeof(float));
    float*  esrc        = (float*)alloc((size_t)NN * 2 * sizeof(float));
    float*  edst        = (float*)alloc((size_t)NN * 2 * sizeof(float));
    float*  pooled      = (float*)alloc((size_t)GG * 128 * sizeof(float));

    // ---- CSR build (bucketed partition) ----
    hipMemsetAsync(bucket_cnt, 0, NBK * sizeof(int), stream);
    bucket_count_kernel<<<(ETOT + 8191) / 8192, 256, 0, stream>>>(ei, bucket_cnt);
    bucket_scan_kernel<<<1, 512, 0, stream>>>(bucket_cnt, bucket_base, gcursor);
    partition_kernel<<<(ETOT + 4095) / 4096, 256, 0, stream>>>(ei, gcursor, part);
    csr_build_kernel<<<NBK, 256, 0, stream>>>(part, bucket_base, row_ptr, csr_src);

    // ---- layer 1: x[N,5] -> bufB[N,64] ----
    feat1_kernel<<<(NN + 3) / 4, 256, 0, stream>>>(
        x, w1, p1w, p1b, as1, ad1, h16, esrc, edst, bufB, NN);
    aggregate64_kernel<<<(NN + 3) / 4, 256, 0, stream>>>(
        h16, (const float2*)esrc, (const float2*)edst, row_ptr, csr_src,
        b1, g1, be1, m1, v1, bufB, NN);

    // ---- layer 2: bufB[N,64] -> bufC[N,128] ----
    tiled_feat_kernel<64><<<NN / 16, 256, 0, stream>>>(
        bufB, w2, p2w, p2b, as2, ad2, h16, esrc, edst, bufC);
    aggregate128_kernel<<<(NN + 3) / 4, 256, 0, stream>>>(
        (const __half2*)h16, (const float2*)esrc, (const float2*)edst, row_ptr, csr_src,
        b2, g2, be2, m2, v2, bufC, NN);

    // ---- layer 3: bufC[N,128] -> bufB[N,128] ----
    tiled_feat_kernel<128><<<NN / 16, 256, 0, stream>>>(
        bufC, w3, p3w, p3b, as3, ad3, h16, esrc, edst, bufB);
    aggregate128_kernel<<<(NN + 3) / 4, 256, 0, stream>>>(
        (const __half2*)h16, (const float2*)esrc, (const float2*)edst, row_ptr, csr_src,
        b3, g3, be3, m3, v3, bufB, NN);

    // ---- pool + head ----
    pool_kernel<<<GG, 128, 0, stream>>>(bufB, batch, pooled);
    head_kernel<<<GG, 128, 0, stream>>>(pooled, fw, fb, g4, be4, m4, v4,
                                        l1w, l1b, l2w, l2b, (float*)d_out);
}

// Round 5
// 807.844 us; speedup vs baseline: 2.3510x; 1.0183x over previous
//
#include <hip/hip_runtime.h>
#include <hip/hip_bf16.h>
#include <hip/hip_fp16.h>

#define NN   100000
#define EE   1600000
#define ETOT (EE + NN)
#define GG   256
#define BNEPS 1e-5f
#define NBK  391          // buckets of 256 nodes: (NN+255)/256

// ---------------- CSR build: bucketed partition (single-writer cache lines) --

__global__ __launch_bounds__(256) void bucket_count_kernel(
    const int* __restrict__ ei, int* __restrict__ bucket_cnt)
{
    __shared__ int cnt[NBK];
    for (int i = threadIdx.x; i < NBK; i += 256) cnt[i] = 0;
    __syncthreads();
    int base = blockIdx.x * 8192;
    for (int k = threadIdx.x; k < 8192; k += 256) {
        int e = base + k;
        if (e < ETOT) {
            int dst = (e < EE) ? ei[EE + e] : (e - EE);
            atomicAdd(&cnt[dst >> 8], 1);
        }
    }
    __syncthreads();
    for (int i = threadIdx.x; i < NBK; i += 256)
        if (cnt[i]) atomicAdd(&bucket_cnt[i], cnt[i]);
}

__global__ __launch_bounds__(512) void bucket_scan_kernel(
    const int* __restrict__ bucket_cnt, int* __restrict__ bucket_base,
    int* __restrict__ gcursor)
{
    __shared__ int s[512];
    int t = threadIdx.x;
    int v = (t < NBK) ? bucket_cnt[t] : 0;
    s[t] = v;
    __syncthreads();
    int x = v;
    for (int o = 1; o < 512; o <<= 1) {
        int y = (t >= o) ? s[t - o] : 0;
        __syncthreads();
        x += y;
        s[t] = x;
        __syncthreads();
    }
    if (t < NBK) { bucket_base[t] = x - v; gcursor[t] = x - v; }
    if (t == 0) bucket_base[NBK] = ETOT;
}

__global__ __launch_bounds__(256) void partition_kernel(
    const int* __restrict__ ei, int* __restrict__ gcursor, int* __restrict__ part)
{
    __shared__ int cnt[NBK];
    __shared__ int basel[NBK];
    for (int i = threadIdx.x; i < NBK; i += 256) cnt[i] = 0;
    __syncthreads();
    int base = blockIdx.x * 4096;
    for (int k = threadIdx.x; k < 4096; k += 256) {
        int e = base + k;
        if (e < ETOT) {
            int dst = (e < EE) ? ei[EE + e] : (e - EE);
            atomicAdd(&cnt[dst >> 8], 1);
        }
    }
    __syncthreads();
    for (int i = threadIdx.x; i < NBK; i += 256) {
        int c = cnt[i];
        basel[i] = c ? atomicAdd(&gcursor[i], c) : 0;
        cnt[i] = 0;   // reuse as intra-block cursor
    }
    __syncthreads();
    for (int k = threadIdx.x; k < 4096; k += 256) {
        int e = base + k;
        if (e < ETOT) {
            int src, dst;
            if (e < EE) { src = ei[e]; dst = ei[EE + e]; }
            else        { src = e - EE; dst = e - EE; }
            int b = dst >> 8;
            int slot = atomicAdd(&cnt[b], 1);
            part[basel[b] + slot] = src | ((dst & 255) << 17);
        }
    }
}

__global__ __launch_bounds__(256) void csr_build_kernel(
    const int* __restrict__ part, const int* __restrict__ bucket_base,
    int* __restrict__ row_ptr, int* __restrict__ csr_src)
{
    __shared__ int deg[256];
    __shared__ int sc[256];
    int b = blockIdx.x;
    int t = threadIdx.x;
    int beg = bucket_base[b], end = bucket_base[b + 1];
    deg[t] = 0;
    __syncthreads();
    for (int j = beg + t; j < end; j += 256)
        atomicAdd(&deg[(part[j] >> 17) & 255], 1);
    __syncthreads();
    int v = deg[t];
    sc[t] = v;
    __syncthreads();
    int x = v;
    for (int o = 1; o < 256; o <<= 1) {
        int y = (t >= o) ? sc[t - o] : 0;
        __syncthreads();
        x += y;
        sc[t] = x;
        __syncthreads();
    }
    int excl = x - v;
    int node = b * 256 + t;
    if (node < NN) row_ptr[node] = beg + excl;
    __syncthreads();
    deg[t] = beg + excl;   // per-node global cursor
    __syncthreads();
    for (int j = beg + t; j < end; j += 256) {
        int pv = part[j];
        int pos = atomicAdd(&deg[(pv >> 17) & 255], 1);
        csr_src[pos] = pv & 0x1FFFF;
    }
    if (b == 0 && t == 0) row_ptr[NN] = ETOT;
}

// ---------------- layer-1 feature transform (K=5, cheap); h stored fp16 ------

__global__ __launch_bounds__(256) void feat1_kernel(
    const float* __restrict__ xin, const float* __restrict__ W,
    const float* __restrict__ pw, const float* __restrict__ pb,
    const float* __restrict__ a_src, const float* __restrict__ a_dst,
    __half* __restrict__ h16, float* __restrict__ esrc, float* __restrict__ edst,
    float* __restrict__ rout, int nN)
{
    constexpr int F_IN = 5, F_OUT = 64;
    int t = threadIdx.x;
    int n = blockIdx.x * 4 + t / F_OUT;
    int f = t % F_OUT;
    if (n >= nN) return;
    float acc = 0.f, racc = 0.f;
#pragma unroll
    for (int k = 0; k < F_IN; ++k) {
        float xv = xin[n * F_IN + k];
        acc  += xv * W[k * F_OUT + f];
        racc += xv * pw[k * F_OUT + f];
    }
    h16[(size_t)n * F_OUT + f] = __float2half_rn(acc);
    rout[(size_t)n * F_OUT + f] = racc + pb[f];
    float es = acc * a_src[f];
    float ed = acc * a_dst[f];
#pragma unroll
    for (int off = 16; off > 0; off >>= 1) {
        es += __shfl_xor(es, off, 32);
        ed += __shfl_xor(ed, off, 32);
    }
    if ((t & 31) == 0) {
        int head = (f >> 5) & 1;
        esrc[n * 2 + head] = es;
        edst[n * 2 + head] = ed;
    }
}

// ---------------- register-tiled feature transform (layers 2,3; F_OUT=128) ----
// Block = 256 threads → 64 nodes × 256 output cols (h[0:128] ‖ rout[0:128]).
// Thread = 4 cols × 16 nodes (acc = 16×float4). Per 64 B weight load → 256
// FMAs (was 64): weight L2 traffic /4 and enough FMA work to hide L2 latency.
// xs4 reads are wave-uniform (g = tid>>6) → LDS broadcast, no conflicts.

template<int F_IN>
__global__ __launch_bounds__(256) void tiled_feat_kernel(
    const float* __restrict__ xin, const float* __restrict__ W,
    const float* __restrict__ pw, const float* __restrict__ pb,
    const float* __restrict__ a_src, const float* __restrict__ a_dst,
    __half* __restrict__ h16, float* __restrict__ esrc, float* __restrict__ edst,
    float* __restrict__ rout)
{
    constexpr int F_OUT = 128;
    constexpr int TILE_M = 64;
    constexpr int K4 = F_IN / 4;
    __shared__ float4 xs4[TILE_M * K4];

    const int tid = threadIdx.x;
    const int cg  = tid & 63;           // col group: 4 cols starting at cg*4
    const int g   = tid >> 6;           // node group: 16 nodes starting at g*16
    const int base = blockIdx.x * TILE_M;

    // cooperative copy of the 64-node x tile into LDS (clamped for last block)
    constexpr int NV = TILE_M * K4;
    const float4* xg4 = (const float4*)xin;
    const int maxv = NN * K4 - 1;
#pragma unroll
    for (int i = tid; i < NV; i += 256) {
        int gi = base * K4 + i;
        xs4[i] = xg4[gi <= maxv ? gi : maxv];
    }
    __syncthreads();

    const int col4 = cg * 4;
    const bool isW = (col4 < F_OUT);
    const float* wbase = isW ? W : pw;
    const int f = isW ? col4 : (col4 - F_OUT);

    float4 acc[16];
#pragma unroll
    for (int i = 0; i < 16; ++i) acc[i] = make_float4(0.f, 0.f, 0.f, 0.f);

    for (int k0 = 0; k0 < F_IN; k0 += 4) {
        float4 w0 = *(const float4*)(wbase + (size_t)(k0 + 0) * F_OUT + f);
        float4 w1 = *(const float4*)(wbase + (size_t)(k0 + 1) * F_OUT + f);
        float4 w2 = *(const float4*)(wbase + (size_t)(k0 + 2) * F_OUT + f);
        float4 w3 = *(const float4*)(wbase + (size_t)(k0 + 3) * F_OUT + f);
#pragma unroll
        for (int i = 0; i < 16; ++i) {
            float4 xv = xs4[(g * 16 + i) * K4 + (k0 >> 2)];
            acc[i].x = fmaf(xv.x, w0.x, acc[i].x);
            acc[i].y = fmaf(xv.x, w0.y, acc[i].y);
            acc[i].z = fmaf(xv.x, w0.z, acc[i].z);
            acc[i].w = fmaf(xv.x, w0.w, acc[i].w);
            acc[i].x = fmaf(xv.y, w1.x, acc[i].x);
            acc[i].y = fmaf(xv.y, w1.y, acc[i].y);
            acc[i].z = fmaf(xv.y, w1.z, acc[i].z);
            acc[i].w = fmaf(xv.y, w1.w, acc[i].w);
            acc[i].x = fmaf(xv.z, w2.x, acc[i].x);
            acc[i].y = fmaf(xv.z, w2.y, acc[i].y);
            acc[i].z = fmaf(xv.z, w2.z, acc[i].z);
            acc[i].w = fmaf(xv.z, w2.w, acc[i].w);
            acc[i].x = fmaf(xv.w, w3.x, acc[i].x);
            acc[i].y = fmaf(xv.w, w3.y, acc[i].y);
            acc[i].z = fmaf(xv.w, w3.z, acc[i].z);
            acc[i].w = fmaf(xv.w, w3.w, acc[i].w);
        }
    }

    if (isW) {
        float4 av = *(const float4*)(a_src + f);
        float4 dv = *(const float4*)(a_dst + f);
        int head = cg >> 4;   // cols 0..63 = head0 (lanes 0..15), 64..127 = head1
#pragma unroll
        for (int i = 0; i < 16; ++i) {
            int node = base + g * 16 + i;
            if (node < NN) {
                __half2* hp = (__half2*)(h16 + (size_t)node * F_OUT + f);
                hp[0] = __floats2half2_rn(acc[i].x, acc[i].y);
                hp[1] = __floats2half2_rn(acc[i].z, acc[i].w);
            }
            float es = acc[i].x * av.x + acc[i].y * av.y + acc[i].z * av.z + acc[i].w * av.w;
            float ed = acc[i].x * dv.x + acc[i].y * dv.y + acc[i].z * dv.z + acc[i].w * dv.w;
#pragma unroll
            for (int off = 8; off > 0; off >>= 1) {
                es += __shfl_xor(es, off, 16);
                ed += __shfl_xor(ed, off, 16);
            }
            if ((cg & 15) == 0 && node < NN) {
                esrc[node * 2 + head] = es;
                edst[node * 2 + head] = ed;
            }
        }
    } else {
        float4 bv = *(const float4*)(pb + f);
#pragma unroll
        for (int i = 0; i < 16; ++i) {
            int node = base + g * 16 + i;
            if (node < NN) {
                float4 r = acc[i];
                r.x += bv.x; r.y += bv.y; r.z += bv.z; r.w += bv.w;
                *(float4*)(rout + (size_t)node * F_OUT + f) = r;
            }
        }
    }
}

// ---------------- fused softmax-aggregate, F=128 (fp16 h, unroll x8) ---------

__global__ __launch_bounds__(256) void aggregate128_kernel(
    const __half2* __restrict__ h2, const float2* __restrict__ esrc,
    const float2* __restrict__ edst,
    const int* __restrict__ row_ptr, const int* __restrict__ csr_src,
    const float* __restrict__ bias, const float* __restrict__ bng,
    const float* __restrict__ bnb, const float* __restrict__ bnm,
    const float* __restrict__ bnv, float* __restrict__ out, int nN)
{
    int w = threadIdx.x >> 6;
    int lane = threadIdx.x & 63;
    int n = blockIdx.x * 4 + w;
    if (n >= nN) return;
    float2 edv = edst[n];
    bool hi = lane >= 32;
    float ed = hi ? edv.y : edv.x;
    int jb = row_ptr[n], je = row_ptr[n + 1];
    float s = 0.f, ax = 0.f, ay = 0.f;
    int j = jb;
    for (; j + 8 <= je; j += 8) {
        int idx[8];
#pragma unroll
        for (int u = 0; u < 8; ++u) idx[u] = csr_src[j + u];
        float2 q[8];
        __half2 v[8];
#pragma unroll
        for (int u = 0; u < 8; ++u) {
            q[u] = esrc[idx[u]];
            v[u] = h2[(size_t)idx[u] * 64 + lane];
        }
#pragma unroll
        for (int u = 0; u < 8; ++u) {
            float a = (hi ? q[u].y : q[u].x) + ed;
            a = (a > 0.f) ? a : 0.2f * a;
            float wgt = __expf(a);
            float2 f = __half22float2(v[u]);
            ax = fmaf(wgt, f.x, ax);
            ay = fmaf(wgt, f.y, ay);
            s += wgt;
        }
    }
    for (; j < je; ++j) {
        int i0 = csr_src[j];
        float2 q0 = esrc[i0];
        __half2 v0 = h2[(size_t)i0 * 64 + lane];
        float a0 = (hi ? q0.y : q0.x) + ed;
        a0 = (a0 > 0.f) ? a0 : 0.2f * a0;
        float w0 = __expf(a0);
        float2 f0 = __half22float2(v0);
        ax = fmaf(w0, f0.x, ax);
        ay = fmaf(w0, f0.y, ay);
        s += w0;
    }
    float inv = 1.f / (s + 1e-16f);
    int f0i = 2 * lane, f1i = 2 * lane + 1;
    float g0 = ax * inv, g1 = ay * inv;
    float o0 = bng[f0i] * (g0 + bias[f0i] - bnm[f0i]) * rsqrtf(bnv[f0i] + BNEPS) + bnb[f0i];
    float o1 = bng[f1i] * (g1 + bias[f1i] - bnm[f1i]) * rsqrtf(bnv[f1i] + BNEPS) + bnb[f1i];
    float2* op = (float2*)(out + (size_t)n * 128) + lane;
    float2 prev = *op;
    prev.x += fmaxf(o0, 0.f);
    prev.y += fmaxf(o1, 0.f);
    *op = prev;
}

// ---------------- fused softmax-aggregate, F=64 (fp16 h, unroll x8) ----------

__global__ __launch_bounds__(256) void aggregate64_kernel(
    const __half* __restrict__ h16, const float2* __restrict__ esrc,
    const float2* __restrict__ edst,
    const int* __restrict__ row_ptr, const int* __restrict__ csr_src,
    const float* __restrict__ bias, const float* __restrict__ bng,
    const float* __restrict__ bnb, const float* __restrict__ bnm,
    const float* __restrict__ bnv, float* __restrict__ out, int nN)
{
    int w = threadIdx.x >> 6;
    int lane = threadIdx.x & 63;
    int n = blockIdx.x * 4 + w;
    if (n >= nN) return;
    float2 edv = edst[n];
    bool hi = lane >= 32;
    float ed = hi ? edv.y : edv.x;
    int jb = row_ptr[n], je = row_ptr[n + 1];
    float s = 0.f, acc = 0.f;
    int j = jb;
    for (; j + 8 <= je; j += 8) {
        int idx[8];
#pragma unroll
        for (int u = 0; u < 8; ++u) idx[u] = csr_src[j + u];
        float2 q[8];
        float v[8];
#pragma unroll
        for (int u = 0; u < 8; ++u) {
            q[u] = esrc[idx[u]];
            v[u] = __half2float(h16[(size_t)idx[u] * 64 + lane]);
        }
#pragma unroll
        for (int u = 0; u < 8; ++u) {
            float a = (hi ? q[u].y : q[u].x) + ed;
            a = (a > 0.f) ? a : 0.2f * a;
            float wgt = __expf(a);
            acc = fmaf(wgt, v[u], acc);
            s += wgt;
        }
    }
    for (; j < je; ++j) {
        int i0 = csr_src[j];
        float2 q0 = esrc[i0];
        float v0 = __half2float(h16[(size_t)i0 * 64 + lane]);
        float a0 = (hi ? q0.y : q0.x) + ed;
        a0 = (a0 > 0.f) ? a0 : 0.2f * a0;
        float w0 = __expf(a0);
        acc = fmaf(w0, v0, acc);
        s += w0;
    }
    int f = lane;
    float g = acc / (s + 1e-16f);
    float v = bng[f] * (g + bias[f] - bnm[f]) * rsqrtf(bnv[f] + BNEPS) + bnb[f];
    out[(size_t)n * 64 + f] = fmaxf(v, 0.f) + out[(size_t)n * 64 + f];
}

// ---------------- pooling (segment mean over sorted batch) ----------------

__global__ __launch_bounds__(128) void pool_kernel(const float* __restrict__ hfin,
                                                   const int* __restrict__ batch,
                                                   float* __restrict__ pooled) {
    int g = blockIdx.x;
    int f = threadIdx.x;
    int lo = 0, hi = NN;
    while (lo < hi) { int mid = (lo + hi) >> 1; if (batch[mid] < g) lo = mid + 1; else hi = mid; }
    int start = lo;
    hi = NN;
    while (lo < hi) { int mid = (lo + hi) >> 1; if (batch[mid] < g + 1) lo = mid + 1; else hi = mid; }
    int end = lo;
    float acc = 0.f;
    for (int i = start; i < end; ++i) acc += hfin[(size_t)i * 128 + f];
    float cnt = (float)(end - start);
    pooled[g * 128 + f] = acc / fmaxf(cnt, 1.0f);
}

// ---------------- MLP head ----------------

__global__ __launch_bounds__(128) void head_kernel(
    const float* __restrict__ pooled, const float* __restrict__ fw, const float* __restrict__ fb,
    const float* __restrict__ g4, const float* __restrict__ be4,
    const float* __restrict__ m4, const float* __restrict__ v4,
    const float* __restrict__ l1w, const float* __restrict__ l1b,
    const float* __restrict__ l2w, const float* __restrict__ l2b,
    float* __restrict__ out)
{
    __shared__ float p[128];
    __shared__ float z1[32];
    __shared__ float z2[32];
    int g = blockIdx.x, t = threadIdx.x;
    p[t] = pooled[g * 128 + t];
    __syncthreads();
    if (t < 32) {
        float acc = fb[t];
        for (int k = 0; k < 128; ++k) acc += p[k] * fw[k * 32 + t];
        float val = g4[t] * (acc - m4[t]) * rsqrtf(v4[t] + BNEPS) + be4[t];
        z1[t] = fmaxf(val, 0.f);
    }
    __syncthreads();
    if (t < 32) {
        float acc = l1b[t];
        for (int k = 0; k < 32; ++k) acc += z1[k] * l1w[k * 32 + t];
        z2[t] = fmaxf(acc, 0.f);
    }
    __syncthreads();
    if (t < 10) {
        float acc = l2b[t];
        for (int k = 0; k < 32; ++k) acc += z2[k] * l2w[k * 10 + t];
        out[g * 10 + t] = acc;
    }
}

// ---------------- launch ----------------

extern "C" void kernel_launch(void* const* d_in, const int* in_sizes, int n_in,
                              void* d_out, int out_size, void* d_ws, size_t ws_size,
                              hipStream_t stream) {
    const float* x     = (const float*)d_in[0];
    const int*   ei    = (const int*)d_in[1];
    const int*   batch = (const int*)d_in[2];
    const float* w1  = (const float*)d_in[3];
    const float* as1 = (const float*)d_in[4];
    const float* ad1 = (const float*)d_in[5];
    const float* b1  = (const float*)d_in[6];
    const float* g1  = (const float*)d_in[7];
    const float* be1 = (const float*)d_in[8];
    const float* m1  = (const float*)d_in[9];
    const float* v1  = (const float*)d_in[10];
    const float* p1w = (const float*)d_in[11];
    const float* p1b = (const float*)d_in[12];
    const float* w2  = (const float*)d_in[13];
    const float* as2 = (const float*)d_in[14];
    const float* ad2 = (const float*)d_in[15];
    const float* b2  = (const float*)d_in[16];
    const float* g2  = (const float*)d_in[17];
    const float* be2 = (const float*)d_in[18];
    const float* m2  = (const float*)d_in[19];
    const float* v2  = (const float*)d_in[20];
    const float* p2w = (const float*)d_in[21];
    const float* p2b = (const float*)d_in[22];
    const float* w3  = (const float*)d_in[23];
    const float* as3 = (const float*)d_in[24];
    const float* ad3 = (const float*)d_in[25];
    const float* b3  = (const float*)d_in[26];
    const float* g3  = (const float*)d_in[27];
    const float* be3 = (const float*)d_in[28];
    const float* m3  = (const float*)d_in[29];
    const float* v3  = (const float*)d_in[30];
    const float* p3w = (const float*)d_in[31];
    const float* p3b = (const float*)d_in[32];
    const float* fw  = (const float*)d_in[33];
    const float* fb  = (const float*)d_in[34];
    const float* g4  = (const float*)d_in[35];
    const float* be4 = (const float*)d_in[36];
    const float* m4  = (const float*)d_in[37];
    const float* v4  = (const float*)d_in[38];
    const float* l1w = (const float*)d_in[39];
    const float* l1b = (const float*)d_in[40];
    const float* l2w = (const float*)d_in[41];
    const float* l2b = (const float*)d_in[42];

    char* ws = (char*)d_ws;
    size_t off = 0;
    auto alloc = [&](size_t bytes) -> char* {
        char* p = ws + off;
        off += (bytes + 255) & ~(size_t)255;
        return p;
    };
    int*    bucket_cnt  = (int*)alloc((NBK) * sizeof(int));
    int*    bucket_base = (int*)alloc((NBK + 1) * sizeof(int));
    int*    gcursor     = (int*)alloc((NBK) * sizeof(int));
    int*    part        = (int*)alloc((size_t)ETOT * sizeof(int));
    int*    row_ptr     = (int*)alloc((NN + 1) * sizeof(int));
    int*    csr_src     = (int*)alloc((size_t)ETOT * sizeof(int));
    __half* h16         = (__half*)alloc((size_t)NN * 128 * sizeof(__half));
    float*  bufB        = (float*)alloc((size_t)NN * 128 * sizeof(float));
    float*  bufC        = (float*)alloc((size_t)NN * 128 * sizeof(float));
    float*  esrc        = (float*)alloc((size_t)NN * 2 * sizeof(float));
    float*  edst        = (float*)alloc((size_t)NN * 2 * sizeof(float));
    float*  pooled      = (float*)alloc((size_t)GG * 128 * sizeof(float));

    // ---- CSR build (bucketed partition) ----
    hipMemsetAsync(bucket_cnt, 0, NBK * sizeof(int), stream);
    bucket_count_kernel<<<(ETOT + 8191) / 8192, 256, 0, stream>>>(ei, bucket_cnt);
    bucket_scan_kernel<<<1, 512, 0, stream>>>(bucket_cnt, bucket_base, gcursor);
    partition_kernel<<<(ETOT + 4095) / 4096, 256, 0, stream>>>(ei, gcursor, part);
    csr_build_kernel<<<NBK, 256, 0, stream>>>(part, bucket_base, row_ptr, csr_src);

    // ---- layer 1: x[N,5] -> bufB[N,64] ----
    feat1_kernel<<<(NN + 3) / 4, 256, 0, stream>>>(
        x, w1, p1w, p1b, as1, ad1, h16, esrc, edst, bufB, NN);
    aggregate64_kernel<<<(NN + 3) / 4, 256, 0, stream>>>(
        h16, (const float2*)esrc, (const float2*)edst, row_ptr, csr_src,
        b1, g1, be1, m1, v1, bufB, NN);

    // ---- layer 2: bufB[N,64] -> bufC[N,128] ----
    tiled_feat_kernel<64><<<(NN + 63) / 64, 256, 0, stream>>>(
        bufB, w2, p2w, p2b, as2, ad2, h16, esrc, edst, bufC);
    aggregate128_kernel<<<(NN + 3) / 4, 256, 0, stream>>>(
        (const __half2*)h16, (const float2*)esrc, (const float2*)edst, row_ptr, csr_src,
        b2, g2, be2, m2, v2, bufC, NN);

    // ---- layer 3: bufC[N,128] -> bufB[N,128] ----
    tiled_feat_kernel<128><<<(NN + 63) / 64, 256, 0, stream>>>(
        bufC, w3, p3w, p3b, as3, ad3, h16, esrc, edst, bufB);
    aggregate128_kernel<<<(NN + 3) / 4, 256, 0, stream>>>(
        (const __half2*)h16, (const float2*)esrc, (const float2*)edst, row_ptr, csr_src,
        b3, g3, be3, m3, v3, bufB, NN);

    // ---- pool + head ----
    pool_kernel<<<GG, 128, 0, stream>>>(bufB, batch, pooled);
    head_kernel<<<GG, 128, 0, stream>>>(pooled, fw, fb, g4, be4, m4, v4,
                                        l1w, l1b, l2w, l2b, (float*)d_out);
}